// Round 13
// baseline (772.337 us; speedup 1.0000x reference)
//
#include <hip/hip_runtime.h>
#include <cmath>

// DenseRnn on MI355X. B=2, N=2048, D=1024, H=8, HD=128.
//
//  wtrans_split_g: Wq/Wk/Wv (one [3072][1024] block), Wcat, Wf2/Wog2 -> bf16
//    hi/lo transposed; Wo plain bf16
//  conv_split: x -> bf16 hi/lo; wcat: [Wf1|Wog1]
//  gemm_bf16_split: qkv = x@[Wq|Wk|Wv]; f1og = x@Wcat; fraw = f1@Wf2; gate = og1@Wog2
//  beta_kernel; prep -> PERM records sb[520] = {k,e,qe (perm), v, sc@512}
//  scan (C=2 chunks x R=8 rows/lane): 16 lanes/col, 8 rows/lane, 8 cols/block,
//    768 x 128-thr blocks = exactly 3 blocks/CU, 1.5 waves/SIMD. Pure-DPP
//    red16 (no swizzle), conflict-free perm b128 reads. Chunk1 basis columns
//    (S0=I, v=0) emit r_t as bf16 hi/lo DIRECTLY; chunk0 emits P0^T bf16.
//    R12 post-mortem: VALUBusy 77% -> issue-bound; this geometry amortizes
//    per-wave overhead over 4 cols (was 2) and cuts reduction to 4 DPP stages.
//  corr_gemm: ov[chunk1] += r @ P0  (per-stream MFMA)
//  post: y = o*sigmoid(gate), per-head RMS, *norm_w -> bf16
//  gemm_bf16: y@Wo -> out

#define SZT ((size_t)4096 * 1024)
#define RECF 520
#define RECSTRIDE 4160     // 8*RECF floats between consecutive tokens of a stream
#define TOKB 16
#define SLOTB 1600         // k 512 | e 512 | qe 512 | v 32 | sc 16 | pad

typedef unsigned short u16;
typedef __attribute__((ext_vector_type(8))) short short8;
typedef __attribute__((ext_vector_type(4))) float f32x4;

__device__ __forceinline__ float sigmf(float x) { return 1.f / (1.f + expf(-x)); }
__device__ __forceinline__ float siluf(float x) { return x * sigmf(x); }
__device__ __forceinline__ u16 f2bf(float f) {
    unsigned int u = __float_as_uint(f);
    unsigned int r = (u + 0x7FFFu + ((u >> 16) & 1u)) >> 16;
    return (u16)r;
}
__device__ __forceinline__ float bf2f(u16 h) { return __uint_as_float((unsigned int)h << 16); }
__device__ __forceinline__ void splitbf(float f, u16& hi, u16& lo) {
    hi = f2bf(f);
    lo = f2bf(f - bf2f(hi));
}

#define GLOAD_LDS16(gp, lp) __builtin_amdgcn_global_load_lds( \
    (const __attribute__((address_space(1))) void*)(gp),      \
    (__attribute__((address_space(3))) void*)(lp), 16, 0, 0)

// ---------------- generic transpose+split: W [K][N] -> WTh/WTl [N][K]
__global__ __launch_bounds__(256) void wtrans_split_g(
    const float* __restrict__ W, u16* __restrict__ WTh, u16* __restrict__ WTl,
    int K, int N)
{
    __shared__ float t[32][33];
    const int tx = threadIdx.x & 31, ty = threadIdx.x >> 5;
    const int n0 = blockIdx.x * 32, k0 = blockIdx.y * 32;
#pragma unroll
    for (int i = 0; i < 4; i++)
        t[ty + i * 8][tx] = W[(size_t)(k0 + ty + i * 8) * N + n0 + tx];
    __syncthreads();
#pragma unroll
    for (int i = 0; i < 4; i++) {
        u16 hi, lo;
        splitbf(t[tx][ty + i * 8], hi, lo);
        WTh[(size_t)(n0 + ty + i * 8) * K + k0 + tx] = hi;
        WTl[(size_t)(n0 + ty + i * 8) * K + k0 + tx] = lo;
    }
}

// ---------------- plain transpose (Wo)
__global__ __launch_bounds__(256) void wtrans(const float* __restrict__ W, u16* __restrict__ WT)
{
    __shared__ float t[32][33];
    const int tx = threadIdx.x & 31, ty = threadIdx.x >> 5;
    const int n0 = blockIdx.x * 32, k0 = blockIdx.y * 32;
#pragma unroll
    for (int i = 0; i < 4; i++)
        t[ty + i * 8][tx] = W[(size_t)(k0 + ty + i * 8) * 1024 + n0 + tx];
    __syncthreads();
#pragma unroll
    for (int i = 0; i < 4; i++)
        WT[(size_t)(n0 + ty + i * 8) * 1024 + k0 + tx] = f2bf(t[tx][ty + i * 8]);
}

// ---------------- fp32 -> bf16 hi/lo elementwise (size = grid*256*8)
__global__ __launch_bounds__(256) void conv_split(
    const float* __restrict__ in, u16* __restrict__ oh, u16* __restrict__ ol)
{
    const size_t i = ((size_t)blockIdx.x * 256 + threadIdx.x) * 8;
    short8 rh, rl;
#pragma unroll
    for (int j = 0; j < 8; j++) {
        u16 hi, lo;
        splitbf(in[i + j], hi, lo);
        rh[j] = (short)hi; rl[j] = (short)lo;
    }
    *(short8*)&oh[i] = rh;
    *(short8*)&ol[i] = rl;
}

// ---------------- concat Wf1|Wog1 -> Wcat [1024][256]
__global__ __launch_bounds__(256) void wcat_kernel(
    const float* __restrict__ Wf1, const float* __restrict__ Wog1, float* __restrict__ Wcat)
{
    const int idx = blockIdx.x * 256 + threadIdx.x;
    const int k = idx >> 8, j = idx & 255;
    Wcat[idx] = (j < 128) ? Wf1[k * 128 + j] : Wog1[k * 128 + j - 128];
}

// ---------------- beta = 2*sigmoid(x @ Wbeta) ; one block per row
__global__ __launch_bounds__(256) void beta_kernel(
    const float* __restrict__ x, const float* __restrict__ Wbeta, float* __restrict__ beta)
{
    const int row = blockIdx.x;
    const int tid = threadIdx.x;
    const int lane = tid & 63, wid = tid >> 6;
    __shared__ float wsum[4][8];
    float4 xv = *(const float4*)&x[(size_t)row * 1024 + tid * 4];
    float p[8];
#pragma unroll
    for (int h = 0; h < 8; h++)
        p[h] = xv.x * Wbeta[(size_t)(tid * 4 + 0) * 8 + h]
             + xv.y * Wbeta[(size_t)(tid * 4 + 1) * 8 + h]
             + xv.z * Wbeta[(size_t)(tid * 4 + 2) * 8 + h]
             + xv.w * Wbeta[(size_t)(tid * 4 + 3) * 8 + h];
#pragma unroll
    for (int off = 32; off >= 1; off >>= 1)
#pragma unroll
        for (int h = 0; h < 8; h++) p[h] += __shfl_xor(p[h], off);
    if (lane == 0)
#pragma unroll
        for (int h = 0; h < 8; h++) wsum[wid][h] = p[h];
    __syncthreads();
    if (tid < 8) {
        float s = wsum[0][tid] + wsum[1][tid] + wsum[2][tid] + wsum[3][tid];
        beta[(size_t)row * 8 + tid] = 2.f * sigmf(s);
    }
}

// ---------------- split bf16 MFMA GEMM: C[M,N] = (Ah+Al)[lda] @ (BTh+BTl)[ldb]^T
__global__ __launch_bounds__(256) void gemm_bf16_split(
    const u16* __restrict__ Ah, const u16* __restrict__ Al,
    const u16* __restrict__ BTh, const u16* __restrict__ BTl,
    float* __restrict__ C, int M, int N, int K, int lda, int ldb)
{
    __shared__ u16 AsH[128 * 32];
    __shared__ u16 AsL[128 * 32];
    __shared__ u16 BsH[128 * 32];
    __shared__ u16 BsL[128 * 32];
    const int tid = threadIdx.x;
    const int lane = tid & 63;
    const int w = tid >> 6;
    const int wr = w >> 1, wc = w & 1;
    const int row0 = blockIdx.y * 128;
    const int col0 = blockIdx.x * 128;
    const int mrow = lane & 15;
    const int kgrp = (lane >> 4) * 8;

    f32x4 acc[4][4] = {};

    const int off0 = w * 1024 + lane * 16;
    const int r0 = off0 >> 6, kl0 = (off0 & 63) >> 1;
    const int off1 = off0 + 4096;
    const int r1 = off1 >> 6, kl1 = (off1 & 63) >> 1;

    for (int kt = 0; kt < K; kt += 32) {
        GLOAD_LDS16(Ah  + (size_t)(row0 + r0) * lda + kt + kl0, (char*)AsH + w * 1024);
        GLOAD_LDS16(Ah  + (size_t)(row0 + r1) * lda + kt + kl1, (char*)AsH + w * 1024 + 4096);
        GLOAD_LDS16(Al  + (size_t)(row0 + r0) * lda + kt + kl0, (char*)AsL + w * 1024);
        GLOAD_LDS16(Al  + (size_t)(row0 + r1) * lda + kt + kl1, (char*)AsL + w * 1024 + 4096);
        GLOAD_LDS16(BTh + (size_t)(col0 + r0) * ldb + kt + kl0, (char*)BsH + w * 1024);
        GLOAD_LDS16(BTh + (size_t)(col0 + r1) * ldb + kt + kl1, (char*)BsH + w * 1024 + 4096);
        GLOAD_LDS16(BTl + (size_t)(col0 + r0) * ldb + kt + kl0, (char*)BsL + w * 1024);
        GLOAD_LDS16(BTl + (size_t)(col0 + r1) * ldb + kt + kl1, (char*)BsL + w * 1024 + 4096);
        __syncthreads();

        short8 aH[4], aL[4], bH[4], bL[4];
#pragma unroll
        for (int mi = 0; mi < 4; ++mi) {
            aH[mi] = *(const short8*)&AsH[(wr * 64 + mi * 16 + mrow) * 32 + kgrp];
            aL[mi] = *(const short8*)&AsL[(wr * 64 + mi * 16 + mrow) * 32 + kgrp];
        }
#pragma unroll
        for (int ni = 0; ni < 4; ++ni) {
            bH[ni] = *(const short8*)&BsH[(wc * 64 + ni * 16 + mrow) * 32 + kgrp];
            bL[ni] = *(const short8*)&BsL[(wc * 64 + ni * 16 + mrow) * 32 + kgrp];
        }
#pragma unroll
        for (int mi = 0; mi < 4; ++mi)
#pragma unroll
            for (int ni = 0; ni < 4; ++ni) {
                acc[mi][ni] = __builtin_amdgcn_mfma_f32_16x16x32_bf16(aH[mi], bH[ni], acc[mi][ni], 0, 0, 0);
                acc[mi][ni] = __builtin_amdgcn_mfma_f32_16x16x32_bf16(aL[mi], bH[ni], acc[mi][ni], 0, 0, 0);
                acc[mi][ni] = __builtin_amdgcn_mfma_f32_16x16x32_bf16(aH[mi], bL[ni], acc[mi][ni], 0, 0, 0);
            }
        __syncthreads();
    }

    const int crow = (lane >> 4) * 4;
#pragma unroll
    for (int mi = 0; mi < 4; ++mi)
#pragma unroll
        for (int ni = 0; ni < 4; ++ni)
#pragma unroll
            for (int j = 0; j < 4; ++j)
                C[(size_t)(row0 + wr * 64 + mi * 16 + crow + j) * N + col0 + wc * 64 + ni * 16 + mrow]
                    = acc[mi][ni][j];
}

// ---------------- correction GEMM: per stream z, ov[t',col] += r[t',:] @ P0T[col,:]^T
__global__ __launch_bounds__(256) void corr_gemm(
    const u16* __restrict__ Ah, const u16* __restrict__ Al,
    const u16* __restrict__ BTh, const u16* __restrict__ BTl,
    float* __restrict__ OV)
{
    __shared__ u16 AsH[128 * 32];
    __shared__ u16 AsL[128 * 32];
    __shared__ u16 BsH[128 * 32];
    __shared__ u16 BsL[128 * 32];
    const int tid = threadIdx.x;
    const int lane = tid & 63;
    const int w = tid >> 6;
    const int wr = w >> 1, wc = w & 1;
    const int row0 = blockIdx.y * 128;
    const int mrow = lane & 15;
    const int kgrp = (lane >> 4) * 8;

    const int bh = blockIdx.z;
    const int b = bh >> 3, h = bh & 7;
    const size_t aoff = (size_t)b * 2097152 + (size_t)h * 128;
    const size_t boff = (size_t)bh * 16384;
    const size_t coff = (size_t)b * 2097152 + (size_t)1048576 + (size_t)h * 128;

    f32x4 acc[4][4] = {};

    const int off0 = w * 1024 + lane * 16;
    const int r0 = off0 >> 6, kl0 = (off0 & 63) >> 1;
    const int off1 = off0 + 4096;
    const int r1 = off1 >> 6, kl1 = (off1 & 63) >> 1;

    for (int kt = 0; kt < 128; kt += 32) {
        GLOAD_LDS16(Ah  + aoff + (size_t)(row0 + r0) * 1024 + kt + kl0, (char*)AsH + w * 1024);
        GLOAD_LDS16(Ah  + aoff + (size_t)(row0 + r1) * 1024 + kt + kl1, (char*)AsH + w * 1024 + 4096);
        GLOAD_LDS16(Al  + aoff + (size_t)(row0 + r0) * 1024 + kt + kl0, (char*)AsL + w * 1024);
        GLOAD_LDS16(Al  + aoff + (size_t)(row0 + r1) * 1024 + kt + kl1, (char*)AsL + w * 1024 + 4096);
        GLOAD_LDS16(BTh + boff + (size_t)r0 * 128 + kt + kl0, (char*)BsH + w * 1024);
        GLOAD_LDS16(BTh + boff + (size_t)r1 * 128 + kt + kl1, (char*)BsH + w * 1024 + 4096);
        GLOAD_LDS16(BTl + boff + (size_t)r0 * 128 + kt + kl0, (char*)BsL + w * 1024);
        GLOAD_LDS16(BTl + boff + (size_t)r1 * 128 + kt + kl1, (char*)BsL + w * 1024 + 4096);
        __syncthreads();

        short8 aH[4], aL[4], bH[4], bL[4];
#pragma unroll
        for (int mi = 0; mi < 4; ++mi) {
            aH[mi] = *(const short8*)&AsH[(wr * 64 + mi * 16 + mrow) * 32 + kgrp];
            aL[mi] = *(const short8*)&AsL[(wr * 64 + mi * 16 + mrow) * 32 + kgrp];
        }
#pragma unroll
        for (int ni = 0; ni < 4; ++ni) {
            bH[ni] = *(const short8*)&BsH[(wc * 64 + ni * 16 + mrow) * 32 + kgrp];
            bL[ni] = *(const short8*)&BsL[(wc * 64 + ni * 16 + mrow) * 32 + kgrp];
        }
#pragma unroll
        for (int mi = 0; mi < 4; ++mi)
#pragma unroll
            for (int ni = 0; ni < 4; ++ni) {
                acc[mi][ni] = __builtin_amdgcn_mfma_f32_16x16x32_bf16(aH[mi], bH[ni], acc[mi][ni], 0, 0, 0);
                acc[mi][ni] = __builtin_amdgcn_mfma_f32_16x16x32_bf16(aL[mi], bH[ni], acc[mi][ni], 0, 0, 0);
                acc[mi][ni] = __builtin_amdgcn_mfma_f32_16x16x32_bf16(aH[mi], bL[ni], acc[mi][ni], 0, 0, 0);
            }
        __syncthreads();
    }

    const int crow = (lane >> 4) * 4;
#pragma unroll
    for (int mi = 0; mi < 4; ++mi)
#pragma unroll
        for (int ni = 0; ni < 4; ++ni)
#pragma unroll
            for (int j = 0; j < 4; ++j) {
                const size_t idx = coff + (size_t)(row0 + wr * 64 + mi * 16 + crow + j) * 1024
                                 + wc * 64 + ni * 16 + mrow;
                OV[idx] += acc[mi][ni][j];
            }
}

// ---------------- plain bf16 MFMA GEMM (final projection)
__global__ __launch_bounds__(256) void gemm_bf16(
    const u16* __restrict__ A, const u16* __restrict__ BT, float* __restrict__ C,
    int M, int N, int K)
{
    __shared__ u16 As[128 * 32];
    __shared__ u16 Bs[128 * 32];
    const int tid = threadIdx.x;
    const int lane = tid & 63;
    const int w = tid >> 6;
    const int wr = w >> 1, wc = w & 1;
    const int row0 = blockIdx.y * 128;
    const int col0 = blockIdx.x * 128;
    const int mrow = lane & 15;
    const int kgrp = (lane >> 4) * 8;

    f32x4 acc[4][4] = {};

    const int off0 = w * 1024 + lane * 16;
    const int r0 = off0 >> 6, kl0 = (off0 & 63) >> 1;
    const int off1 = off0 + 4096;
    const int r1 = off1 >> 6, kl1 = (off1 & 63) >> 1;

    for (int kt = 0; kt < K; kt += 32) {
        GLOAD_LDS16(A  + (size_t)(row0 + r0) * K + kt + kl0, (char*)As + w * 1024);
        GLOAD_LDS16(A  + (size_t)(row0 + r1) * K + kt + kl1, (char*)As + w * 1024 + 4096);
        GLOAD_LDS16(BT + (size_t)(col0 + r0) * K + kt + kl0, (char*)Bs + w * 1024);
        GLOAD_LDS16(BT + (size_t)(col0 + r1) * K + kt + kl1, (char*)Bs + w * 1024 + 4096);
        __syncthreads();

        short8 aF[4], bF[4];
#pragma unroll
        for (int mi = 0; mi < 4; ++mi)
            aF[mi] = *(const short8*)&As[(wr * 64 + mi * 16 + mrow) * 32 + kgrp];
#pragma unroll
        for (int ni = 0; ni < 4; ++ni)
            bF[ni] = *(const short8*)&Bs[(wc * 64 + ni * 16 + mrow) * 32 + kgrp];
#pragma unroll
        for (int mi = 0; mi < 4; ++mi)
#pragma unroll
            for (int ni = 0; ni < 4; ++ni)
                acc[mi][ni] = __builtin_amdgcn_mfma_f32_16x16x32_bf16(aF[mi], bF[ni], acc[mi][ni], 0, 0, 0);
        __syncthreads();
    }

    const int crow = (lane >> 4) * 4;
#pragma unroll
    for (int mi = 0; mi < 4; ++mi)
#pragma unroll
        for (int ni = 0; ni < 4; ++ni)
#pragma unroll
            for (int j = 0; j < 4; ++j)
                C[(size_t)(row0 + wr * 64 + mi * 16 + crow + j) * N + col0 + wc * 64 + ni * 16 + mrow]
                    = acc[mi][ni][j];
}

// ---------------- prep: block per (row,h), 128 thr. PERM record layout:
// perm(j) = ((j&4)<<4) + ((j>>3)<<2) + (j&3): lane rg reads rows rg*8..rg*8+7
// as two float4 at bytes rg*16 and 256+rg*16 (conflict-free, R10-verified).
__global__ __launch_bounds__(128) void prep_kernel(
    const float* __restrict__ qkv, const float* __restrict__ fraw,
    const float* __restrict__ beta, float* __restrict__ sb)
{
    const int gid = blockIdx.x;
    const int h = gid & 7;
    const int row = gid >> 3;
    const int tid = threadIdx.x;
    const int col = h * 128 + tid;
    const size_t rb3 = (size_t)row * 3072;

    __shared__ float red[3][128];

    const float ksil = siluf(qkv[rb3 + 1024 + col]);
    red[0][tid] = ksil * ksil;
    __syncthreads();
    for (int off = 64; off > 0; off >>= 1) {
        if (tid < off) red[0][tid] += red[0][tid + off];
        __syncthreads();
    }
    const float rn = rsqrtf(red[0][0] + 1e-6f);
    __syncthreads();

    const float kn = ksil * rn;
    const float e  = sigmf(fraw[(size_t)row * 1024 + col]);
    const float qs = siluf(qkv[rb3 + col]);
    const float vs = siluf(qkv[rb3 + 2048 + col]);
    const float kev = e * kn;
    const float qev = e * qs;

    red[0][tid] = kev * kn;   // c
    red[1][tid] = qs * kev;   // d1
    red[2][tid] = qs * kn;    // d2
    __syncthreads();
    for (int off = 64; off > 0; off >>= 1) {
        if (tid < off) {
            red[0][tid] += red[0][tid + off];
            red[1][tid] += red[1][tid + off];
            red[2][tid] += red[2][tid + off];
        }
        __syncthreads();
    }

    const int p = ((tid & 4) << 4) + ((tid >> 3) << 2) + (tid & 3);
    float* o = sb + (size_t)gid * RECF;
    o[p]         = kn;
    o[128 + p]   = e;
    o[256 + p]   = qev;
    o[384 + tid] = vs;
    if (tid == 0) {
        o[512] = beta[(size_t)row * 8 + h];
        o[513] = red[0][0];
        o[514] = red[1][0];
        o[515] = red[2][0];
    }
}

// ---------------- scan
// 16-lane sum, pure DPP (VALU-only, no LDS-pipe op in the chain).
__device__ __forceinline__ float red16(float x)
{
    x += __int_as_float(__builtin_amdgcn_mov_dpp(__float_as_int(x), 0xB1,  0xF, 0xF, true)); // quad xor1
    x += __int_as_float(__builtin_amdgcn_mov_dpp(__float_as_int(x), 0x4E,  0xF, 0xF, true)); // quad xor2
    x += __int_as_float(__builtin_amdgcn_mov_dpp(__float_as_int(x), 0x141, 0xF, 0xF, true)); // row_half_mirror
    x += __int_as_float(__builtin_amdgcn_mov_dpp(__float_as_int(x), 0x140, 0xF, 0xF, true)); // row_mirror
    return x;
}

struct TR { float4 ka, kb, ea, eb, qa, qb, sc; float vc; };

__device__ __forceinline__ void ldtok(const char* __restrict__ rec, int rg, int cl, TR& T)
{
    T.ka = *(const float4*)(rec + rg * 16);
    T.kb = *(const float4*)(rec + 256 + rg * 16);
    T.ea = *(const float4*)(rec + 512 + rg * 16);
    T.eb = *(const float4*)(rec + 768 + rg * 16);
    T.qa = *(const float4*)(rec + 1024 + rg * 16);
    T.qb = *(const float4*)(rec + 1280 + rg * 16);
    T.vc = *(const float*)(rec + 1536 + cl * 4);
    T.sc = *(const float4*)(rec + 1568);
}

#define STEP(T, SOFF)                                                                   \
  {                                                                                     \
    const float m0 = T.ka.x * S0, m1 = T.ka.y * S1, m2 = T.ka.z * S2, m3 = T.ka.w * S3; \
    const float m4 = T.kb.x * S4, m5 = T.kb.y * S5, m6 = T.kb.z * S6, m7 = T.kb.w * S7; \
    float bS  = ((m0 + m1) + (m2 + m3)) + ((m4 + m5) + (m6 + m7));                      \
    float keS = ((T.ea.x * m0 + T.ea.y * m1) + (T.ea.z * m2 + T.ea.w * m3))             \
              + ((T.eb.x * m4 + T.eb.y * m5) + (T.eb.z * m6 + T.eb.w * m7));            \
    float qeS = ((T.qa.x * S0 + T.qa.y * S1) + (T.qa.z * S2 + T.qa.w * S3))             \
              + ((T.qb.x * S4 + T.qb.y * S5) + (T.qb.z * S6 + T.qb.w * S7));            \
    bS = red16(bS); keS = red16(keS); qeS = red16(qeS);                                 \
    const float bSb = T.sc.x * bS;                                                      \
    const float ks  = keS - bSb * T.sc.y;                                               \
    const float wv  = T.vc - T.sc.x * ks;                                               \
    const float o   = (qeS - bSb * T.sc.z) + wv * T.sc.w;                               \
    S0 = T.ea.x * (S0 - bSb * T.ka.x) + wv * T.ka.x;                                    \
    S1 = T.ea.y * (S1 - bSb * T.ka.y) + wv * T.ka.y;                                    \
    S2 = T.ea.z * (S2 - bSb * T.ka.z) + wv * T.ka.z;                                    \
    S3 = T.ea.w * (S3 - bSb * T.ka.w) + wv * T.ka.w;                                    \
    S4 = T.eb.x * (S4 - bSb * T.kb.x) + wv * T.kb.x;                                    \
    S5 = T.eb.y * (S5 - bSb * T.kb.y) + wv * T.kb.y;                                    \
    S6 = T.eb.z * (S6 - bSb * T.kb.z) + wv * T.kb.z;                                    \
    S7 = T.eb.w * (S7 - bSb * T.kb.w) + wv * T.kb.w;                                    \
    if (rg == 0) {                                                                      \
        if (basis) {                                                                    \
            u16 hi, lo; splitbf(o, hi, lo);                                             \
            rbh[oidx + (size_t)(SOFF) * 1024] = hi;                                     \
            rbl[oidx + (size_t)(SOFF) * 1024] = lo;                                     \
        } else {                                                                        \
            ov[oidx + (size_t)(SOFF) * 1024] = o;                                       \
        }                                                                               \
    }                                                                                   \
  }

#define SBAR __builtin_amdgcn_sched_barrier(0)

__device__ __forceinline__ void stage_batch(
    const float* __restrict__ p0, char* ldsbuf, int t0, int w, int lane, int vg)
{
    for (int s = w; s < TOKB; s += 2) {
        const char* src = (const char*)(p0 + (size_t)(t0 + s) * RECSTRIDE);
        char* dst = ldsbuf + s * SLOTB;
        GLOAD_LDS16(src + lane * 16, dst);                               // k,e perm (1024B)
        if (lane < 32) GLOAD_LDS16(src + 1024 + lane * 16, dst + 1024);  // qe perm (512B)
        if (lane < 2)  GLOAD_LDS16(src + 1536 + vg * 32 + lane * 16, dst + 1536); // v slice
        if (lane == 0) GLOAD_LDS16(src + 2048, dst + 1568);              // sc
    }
}

// 768 blocks x 128 threads (2 waves) = exactly 3 blocks/CU, 1.5 waves/SIMD.
// bh = blk&15 keeps a stream's blocks on one XCD. gidx = blk>>4 in [0,48):
//   gidx<16 -> chunk0 (t 0..1023), real cols cg*8..cg*8+7, emits P0^T bf16.
//   else    -> chunk1 (t 1024..2047), cg2 = gidx-16 in [0,32):
//              colx = cg2*8+cl; colx<128 real (corrected later), >=128 basis
//              (S0=I, v=0) -> r_t emitted as bf16 hi/lo directly.
__global__ __launch_bounds__(128) void scan_kernel(
    const float* __restrict__ sb, float* __restrict__ ov,
    u16* __restrict__ rbh, u16* __restrict__ rbl,
    u16* __restrict__ pTh, u16* __restrict__ pTl)
{
    __shared__ char lds[2 * TOKB * SLOTB];   // 51200 B

    const int tid = threadIdx.x;
    const int blk = blockIdx.x;
    const int cl = tid >> 4;      // 0..7
    const int rg = tid & 15;
    const int w = tid >> 6;
    const int lane = tid & 63;

    const int bh = blk & 15;
    const int gidx = blk >> 4;

    int vg, tstart, colx;
    bool chunk0, basis = false;
    if (gidx < 16) {
        colx = gidx * 8 + cl; vg = gidx; tstart = 0; chunk0 = true;
    } else {
        const int cg2 = gidx - 16;
        colx = cg2 * 8 + cl; vg = cg2 & 15; tstart = 1024; chunk0 = false;
        basis = colx >= 128;
    }
    const int b = bh >> 3, h = bh & 7;
    const size_t base = (size_t)b * 2048 * 8 + h;
    const float* p0 = sb + base * RECF + (size_t)tstart * RECSTRIDE;

    size_t oidx;
    if (chunk0)      oidx = base * 128 + colx;
    else if (!basis) oidx = base * 128 + (size_t)1048576 + colx;
    else             oidx = base * 128 + (colx - 128);

    const float vmask = basis ? 0.f : 1.f;
    float S0, S1, S2, S3, S4, S5, S6, S7;
    if (basis) {
        const int jb = colx - 128;
        S0 = (rg * 8 + 0 == jb) ? 1.f : 0.f;
        S1 = (rg * 8 + 1 == jb) ? 1.f : 0.f;
        S2 = (rg * 8 + 2 == jb) ? 1.f : 0.f;
        S3 = (rg * 8 + 3 == jb) ? 1.f : 0.f;
        S4 = (rg * 8 + 4 == jb) ? 1.f : 0.f;
        S5 = (rg * 8 + 5 == jb) ? 1.f : 0.f;
        S6 = (rg * 8 + 6 == jb) ? 1.f : 0.f;
        S7 = (rg * 8 + 7 == jb) ? 1.f : 0.f;
    } else { S0 = S1 = S2 = S3 = S4 = S5 = S6 = S7 = 0.f; }

    stage_batch(p0, lds, 0, w, lane, vg);
    __syncthreads();

    int cur = 0;
    for (int t0 = 0; t0 < 1024; t0 += TOKB) {
        if (t0 + TOKB < 1024)
            stage_batch(p0, lds + (cur ^ 1) * (TOKB * SLOTB), t0 + TOKB, w, lane, vg);

        const char* bufp = lds + cur * (TOKB * SLOTB);
        TR A, B;
        ldtok(bufp, rg, cl, A); A.vc *= vmask; SBAR;
#pragma unroll
        for (int s = 0; s < TOKB; s += 2) {
            ldtok(bufp + (s + 1) * SLOTB, rg, cl, B); B.vc *= vmask; SBAR;
            STEP(A, s);
            if (s + 2 < TOKB) { ldtok(bufp + (s + 2) * SLOTB, rg, cl, A); A.vc *= vmask; SBAR; }
            STEP(B, s + 1);
        }
        __syncthreads();
        cur ^= 1;
        oidx += (size_t)TOKB * 1024;
    }

    if (chunk0) {
        // emit P0^T (S^T: [col][row]) as bf16 hi/lo directly
        float Sv[8] = {S0, S1, S2, S3, S4, S5, S6, S7};
        short8 h8, l8;
#pragma unroll
        for (int i = 0; i < 8; i++) {
            u16 hi, lo; splitbf(Sv[i], hi, lo);
            h8[i] = (short)hi; l8[i] = (short)lo;
        }
        const size_t po = (size_t)bh * 16384 + (size_t)colx * 128 + rg * 8;
        *(short8*)(pTh + po) = h8;
        *(short8*)(pTl + po) = l8;
    }
}

// ---------------- post: y = o*sigmoid(gate); per-head RMS; *norm_w -> bf16
__global__ __launch_bounds__(128) void post_kernel(
    const float* __restrict__ ov, const float* __restrict__ gate,
    const float* __restrict__ normw, u16* __restrict__ ybf)
{
    const int gid = blockIdx.x;
    const int h = gid & 7;
    const int row = gid >> 3;
    const int tid = threadIdx.x;
    const int col = h * 128 + tid;

    __shared__ float red[128];

    const float o = ov[(size_t)row * 1024 + col];
    const float y = o * sigmf(gate[(size_t)row * 1024 + col]);

    red[tid] = y * y;
    __syncthreads();
    for (int off = 64; off > 0; off >>= 1) {
        if (tid < off) red[tid] += red[tid + off];
        __syncthreads();
    }
    const float rms = rsqrtf(red[0] * (1.f / 128.f) + 1e-6f);
    ybf[(size_t)row * 1024 + col] = f2bf(y * rms * normw[col]);
}

extern "C" void kernel_launch(void* const* d_in, const int* in_sizes, int n_in,
                              void* d_out, int out_size, void* d_ws, size_t ws_size,
                              hipStream_t stream)
{
    const float* x     = (const float*)d_in[0];
    const float* Wq    = (const float*)d_in[1];
    const float* Wk    = (const float*)d_in[2];
    const float* Wv    = (const float*)d_in[3];
    const float* Wf1   = (const float*)d_in[4];
    const float* Wf2   = (const float*)d_in[5];
    const float* Wbeta = (const float*)d_in[6];
    const float* Wog1  = (const float*)d_in[7];
    const float* Wog2  = (const float*)d_in[8];
    const float* normw = (const float*)d_in[9];
    const float* Wo    = (const float*)d_in[10];
    float* out = (float*)d_out;

    float* ws    = (float*)d_ws;
    float* qkv   = ws;                                 // 12M f [4096x3072]
    float* sb    = qkv + 3 * SZT;                      // 17.04M f
    float* ovr   = sb + (size_t)32768 * RECF;          // 4M f (early: Wqkv splits; then fraw; then ov)
    float* rbspace = ovr + SZT;                        // 4M f -> rbh/rbl u16
    float* pbspace = rbspace + SZT;                    // 256K f -> pTh/pTl u16
    float* wot   = pbspace + 262144;                   // 0.5M f
    float* wcatT = wot + 524288;                       // 0.25M f
    float* wfog  = wcatT + 262144;                     // 0.25M f
    float* f1sp  = wfog + 262144;                      // 1M f
    float* betap = f1sp + 1048576;                     // 32K f
    float* xsp   = betap + 32768;                      // 4M f (xh/xl)

    // early buffers inside sb (dead before prep writes sb)
    float* wcat = sb;                                  // 0.26M f
    float* f1og = wcat + 262144;                       // 1M f

    u16* WqkvTh = (u16*)ovr;                           // 3M u16
    u16* WqkvTl = WqkvTh + (size_t)3 * 1024 * 1024;    // 3M u16
    float* fraw = ovr;                                 // after qkv gemm

    u16* xh  = (u16*)xsp;
    u16* xl  = xh + SZT;

    u16* rbh = (u16*)rbspace;                          // 4M u16
    u16* rbl = rbh + SZT;                              // wait: rbspace is 4M f = 16MB; rbh+rbl = 8M u16 = 16MB ✓
    u16* pTh = (u16*)pbspace;                          // 256K u16
    u16* pTl = pTh + 262144;                           // 256K u16 (pbspace 256K f = 1MB ✓)

    u16* WoT    = (u16*)wot;
    u16* WcatTh = (u16*)wcatT;
    u16* WcatTl = WcatTh + (size_t)256 * 1024;
    u16* Wf2Th  = (u16*)wfog;
    u16* Wf2Tl  = Wf2Th + (size_t)1024 * 128;
    u16* Wog2Th = Wf2Tl + (size_t)1024 * 128;
    u16* Wog2Tl = Wog2Th + (size_t)1024 * 128;
    u16* f1ogh  = (u16*)f1sp;
    u16* f1ogl  = f1ogh + (size_t)4096 * 256;

    float* gate = qkv;                                 // qkv dead after prep
    u16*   ybf  = (u16*)(qkv + SZT);

    dim3 b256(256), b128(128);

    wtrans_split_g<<<dim3(32, 32), b256, 0, stream>>>(Wq, WqkvTh, WqkvTl, 1024, 1024);
    wtrans_split_g<<<dim3(32, 32), b256, 0, stream>>>(Wk, WqkvTh + (size_t)1024 * 1024, WqkvTl + (size_t)1024 * 1024, 1024, 1024);
    wtrans_split_g<<<dim3(32, 32), b256, 0, stream>>>(Wv, WqkvTh + (size_t)2048 * 1024, WqkvTl + (size_t)2048 * 1024, 1024, 1024);
    wtrans<<<dim3(32, 32), b256, 0, stream>>>(Wo, WoT);
    conv_split<<<2048, b256, 0, stream>>>(x, xh, xl);
    wcat_kernel<<<1024, b256, 0, stream>>>(Wf1, Wog1, wcat);
    wtrans_split_g<<<dim3(8, 32), b256, 0, stream>>>(wcat, WcatTh, WcatTl, 1024, 256);
    wtrans_split_g<<<dim3(32, 4), b256, 0, stream>>>(Wf2, Wf2Th, Wf2Tl, 128, 1024);
    wtrans_split_g<<<dim3(32, 4), b256, 0, stream>>>(Wog2, Wog2Th, Wog2Tl, 128, 1024);
    beta_kernel<<<4096, b256, 0, stream>>>(x, Wbeta, betap);

    gemm_bf16_split<<<dim3(24, 32), b256, 0, stream>>>(xh, xl, WqkvTh, WqkvTl, qkv, 4096, 3072, 1024, 1024, 1024);
    gemm_bf16_split<<<dim3(2, 32), b256, 0, stream>>>(xh, xl, WcatTh, WcatTl, f1og, 4096, 256, 1024, 1024, 1024);
    conv_split<<<512, b256, 0, stream>>>(f1og, f1ogh, f1ogl);
    gemm_bf16_split<<<dim3(8, 32), b256, 0, stream>>>(f1ogh, f1ogl, Wf2Th, Wf2Tl, fraw, 4096, 1024, 128, 256, 128);

    prep_kernel<<<32768, b128, 0, stream>>>(qkv, fraw, betap, sb);
    gemm_bf16_split<<<dim3(8, 32), b256, 0, stream>>>(f1ogh + 128, f1ogl + 128, Wog2Th, Wog2Tl, gate, 4096, 1024, 128, 256, 128);

    scan_kernel<<<768, b128, 0, stream>>>(sb, ovr, rbh, rbl, pTh, pTl);

    corr_gemm<<<dim3(1, 8, 16), b256, 0, stream>>>(rbh, rbl, pTh, pTl, ovr);

    post_kernel<<<32768, b128, 0, stream>>>(ovr, gate, normw, ybf);

    gemm_bf16<<<dim3(8, 32), b256, 0, stream>>>(ybf, WoT, out, 4096, 1024, 1024);
}

// Round 14
// 729.354 us; speedup vs baseline: 1.0589x; 1.0589x over previous
//
#include <hip/hip_runtime.h>
#include <cmath>

// DenseRnn on MI355X. B=2, N=2048, D=1024, H=8, HD=128.
//
//  wtrans_split_qkv (z=3): Wq/Wk/Wv -> bf16 hi/lo transposed (one launch)
//  wtrans_split4 (z=4): Wf1,Wog1 -> WcatT rows 0-127/128-255; Wf2,Wog2 -> T
//  wtrans: Wo plain bf16; conv_split: x -> bf16 hi/lo
//  gemm_bf16_split: qkv = x@[Wq|Wk|Wv]; f1og = x@Wcat; fraw = f1@Wf2; gate = og1@Wog2
//  beta_kernel; prep -> records sb[520] = {k,e,qe,v, sc@512} (plain layout)
//  scan (C=2, R12 geometry): 32 lanes/col x 4 rows/lane, 768 x 256-thr blocks
//    = 3072 waves = 3/SIMD (R13 post-mortem: fewer waves lost more to latency
//    than fewer instructions gained). 4-DPP+swizzle red32. Chunk1 basis cols
//    (S0=I, v=0) emit r_t bf16 hi/lo directly; chunk0 emits P0^T bf16.
//  corr_gemm: ov[chunk1] += r @ P0 (per-stream MFMA)
//  post: y = o*sigmoid(gate), per-head RMS, *norm_w -> bf16
//  gemm_bf16: y@Wo -> out

#define SZT ((size_t)4096 * 1024)
#define RECF 520
#define RECSTRIDE 4160     // 8*RECF floats between consecutive tokens of a stream
#define TOKB 16
#define SLOTB 1600         // k 512 | e 512 | qe 512 | v 32 | sc 16 | pad

typedef unsigned short u16;
typedef __attribute__((ext_vector_type(8))) short short8;
typedef __attribute__((ext_vector_type(4))) short su4;
typedef __attribute__((ext_vector_type(4))) float f32x4;

__device__ __forceinline__ float sigmf(float x) { return 1.f / (1.f + expf(-x)); }
__device__ __forceinline__ float siluf(float x) { return x * sigmf(x); }
__device__ __forceinline__ u16 f2bf(float f) {
    unsigned int u = __float_as_uint(f);
    unsigned int r = (u + 0x7FFFu + ((u >> 16) & 1u)) >> 16;
    return (u16)r;
}
__device__ __forceinline__ float bf2f(u16 h) { return __uint_as_float((unsigned int)h << 16); }
__device__ __forceinline__ void splitbf(float f, u16& hi, u16& lo) {
    hi = f2bf(f);
    lo = f2bf(f - bf2f(hi));
}

#define GLOAD_LDS16(gp, lp) __builtin_amdgcn_global_load_lds( \
    (const __attribute__((address_space(1))) void*)(gp),      \
    (__attribute__((address_space(3))) void*)(lp), 16, 0, 0)

// ---------------- transpose+split body (32x32 tile)
__device__ __forceinline__ void wtrans_split_body(
    const float* __restrict__ W, u16* __restrict__ WTh, u16* __restrict__ WTl,
    int K, int N, int bx, int by)
{
    __shared__ float t[32][33];
    const int tx = threadIdx.x & 31, ty = threadIdx.x >> 5;
    const int n0 = bx * 32, k0 = by * 32;
#pragma unroll
    for (int i = 0; i < 4; i++)
        t[ty + i * 8][tx] = W[(size_t)(k0 + ty + i * 8) * N + n0 + tx];
    __syncthreads();
#pragma unroll
    for (int i = 0; i < 4; i++) {
        u16 hi, lo;
        splitbf(t[tx][ty + i * 8], hi, lo);
        WTh[(size_t)(n0 + ty + i * 8) * K + k0 + tx] = hi;
        WTl[(size_t)(n0 + ty + i * 8) * K + k0 + tx] = lo;
    }
}

// Wq/Wk/Wv -> WqkvT (z selects source), all 1024x1024
__global__ __launch_bounds__(256) void wtrans_split_qkv(
    const float* __restrict__ Wq, const float* __restrict__ Wk, const float* __restrict__ Wv,
    u16* __restrict__ WTh, u16* __restrict__ WTl)
{
    const int z = blockIdx.z;
    const float* W = (z == 0) ? Wq : (z == 1) ? Wk : Wv;
    wtrans_split_body(W, WTh + (size_t)z * 1024 * 1024, WTl + (size_t)z * 1024 * 1024,
                      1024, 1024, blockIdx.x, blockIdx.y);
}

// z=0: Wf1 [1024x128] -> WcatT rows 0-127 ; z=1: Wog1 -> WcatT rows 128-255
// z=2: Wf2 [128x1024] -> Wf2T ; z=3: Wog2 -> Wog2T.  grid.x = 128 blocks each.
__global__ __launch_bounds__(256) void wtrans_split4(
    const float* __restrict__ Wf1, const float* __restrict__ Wog1,
    const float* __restrict__ Wf2, const float* __restrict__ Wog2,
    u16* __restrict__ WcatTh, u16* __restrict__ WcatTl,
    u16* __restrict__ Wf2Th, u16* __restrict__ Wf2Tl,
    u16* __restrict__ Wog2Th, u16* __restrict__ Wog2Tl)
{
    const int z = blockIdx.z;
    const float* W; u16 *Th, *Tl; int K, N;
    if (z == 0)      { W = Wf1;  Th = WcatTh; Tl = WcatTl; K = 1024; N = 128; }
    else if (z == 1) { W = Wog1; Th = WcatTh + (size_t)128 * 1024; Tl = WcatTl + (size_t)128 * 1024; K = 1024; N = 128; }
    else if (z == 2) { W = Wf2;  Th = Wf2Th;  Tl = Wf2Tl;  K = 128; N = 1024; }
    else             { W = Wog2; Th = Wog2Th; Tl = Wog2Tl; K = 128; N = 1024; }
    const int nbx = N / 32;
    wtrans_split_body(W, Th, Tl, K, N, blockIdx.x % nbx, blockIdx.x / nbx);
}

// ---------------- plain transpose (Wo)
__global__ __launch_bounds__(256) void wtrans(const float* __restrict__ W, u16* __restrict__ WT)
{
    __shared__ float t[32][33];
    const int tx = threadIdx.x & 31, ty = threadIdx.x >> 5;
    const int n0 = blockIdx.x * 32, k0 = blockIdx.y * 32;
#pragma unroll
    for (int i = 0; i < 4; i++)
        t[ty + i * 8][tx] = W[(size_t)(k0 + ty + i * 8) * 1024 + n0 + tx];
    __syncthreads();
#pragma unroll
    for (int i = 0; i < 4; i++)
        WT[(size_t)(n0 + ty + i * 8) * 1024 + k0 + tx] = f2bf(t[tx][ty + i * 8]);
}

// ---------------- fp32 -> bf16 hi/lo elementwise (size = grid*256*8)
__global__ __launch_bounds__(256) void conv_split(
    const float* __restrict__ in, u16* __restrict__ oh, u16* __restrict__ ol)
{
    const size_t i = ((size_t)blockIdx.x * 256 + threadIdx.x) * 8;
    short8 rh, rl;
#pragma unroll
    for (int j = 0; j < 8; j++) {
        u16 hi, lo;
        splitbf(in[i + j], hi, lo);
        rh[j] = (short)hi; rl[j] = (short)lo;
    }
    *(short8*)&oh[i] = rh;
    *(short8*)&ol[i] = rl;
}

// ---------------- beta = 2*sigmoid(x @ Wbeta) ; one block per row
__global__ __launch_bounds__(256) void beta_kernel(
    const float* __restrict__ x, const float* __restrict__ Wbeta, float* __restrict__ beta)
{
    const int row = blockIdx.x;
    const int tid = threadIdx.x;
    const int lane = tid & 63, wid = tid >> 6;
    __shared__ float wsum[4][8];
    float4 xv = *(const float4*)&x[(size_t)row * 1024 + tid * 4];
    float p[8];
#pragma unroll
    for (int h = 0; h < 8; h++)
        p[h] = xv.x * Wbeta[(size_t)(tid * 4 + 0) * 8 + h]
             + xv.y * Wbeta[(size_t)(tid * 4 + 1) * 8 + h]
             + xv.z * Wbeta[(size_t)(tid * 4 + 2) * 8 + h]
             + xv.w * Wbeta[(size_t)(tid * 4 + 3) * 8 + h];
#pragma unroll
    for (int off = 32; off >= 1; off >>= 1)
#pragma unroll
        for (int h = 0; h < 8; h++) p[h] += __shfl_xor(p[h], off);
    if (lane == 0)
#pragma unroll
        for (int h = 0; h < 8; h++) wsum[wid][h] = p[h];
    __syncthreads();
    if (tid < 8) {
        float s = wsum[0][tid] + wsum[1][tid] + wsum[2][tid] + wsum[3][tid];
        beta[(size_t)row * 8 + tid] = 2.f * sigmf(s);
    }
}

// ---------------- split bf16 MFMA GEMM: C[M,N] = (Ah+Al)[lda] @ (BTh+BTl)[ldb]^T
__global__ __launch_bounds__(256) void gemm_bf16_split(
    const u16* __restrict__ Ah, const u16* __restrict__ Al,
    const u16* __restrict__ BTh, const u16* __restrict__ BTl,
    float* __restrict__ C, int M, int N, int K, int lda, int ldb)
{
    __shared__ u16 AsH[128 * 32];
    __shared__ u16 AsL[128 * 32];
    __shared__ u16 BsH[128 * 32];
    __shared__ u16 BsL[128 * 32];
    const int tid = threadIdx.x;
    const int lane = tid & 63;
    const int w = tid >> 6;
    const int wr = w >> 1, wc = w & 1;
    const int row0 = blockIdx.y * 128;
    const int col0 = blockIdx.x * 128;
    const int mrow = lane & 15;
    const int kgrp = (lane >> 4) * 8;

    f32x4 acc[4][4] = {};

    const int off0 = w * 1024 + lane * 16;
    const int r0 = off0 >> 6, kl0 = (off0 & 63) >> 1;
    const int off1 = off0 + 4096;
    const int r1 = off1 >> 6, kl1 = (off1 & 63) >> 1;

    for (int kt = 0; kt < K; kt += 32) {
        GLOAD_LDS16(Ah  + (size_t)(row0 + r0) * lda + kt + kl0, (char*)AsH + w * 1024);
        GLOAD_LDS16(Ah  + (size_t)(row0 + r1) * lda + kt + kl1, (char*)AsH + w * 1024 + 4096);
        GLOAD_LDS16(Al  + (size_t)(row0 + r0) * lda + kt + kl0, (char*)AsL + w * 1024);
        GLOAD_LDS16(Al  + (size_t)(row0 + r1) * lda + kt + kl1, (char*)AsL + w * 1024 + 4096);
        GLOAD_LDS16(BTh + (size_t)(col0 + r0) * ldb + kt + kl0, (char*)BsH + w * 1024);
        GLOAD_LDS16(BTh + (size_t)(col0 + r1) * ldb + kt + kl1, (char*)BsH + w * 1024 + 4096);
        GLOAD_LDS16(BTl + (size_t)(col0 + r0) * ldb + kt + kl0, (char*)BsL + w * 1024);
        GLOAD_LDS16(BTl + (size_t)(col0 + r1) * ldb + kt + kl1, (char*)BsL + w * 1024 + 4096);
        __syncthreads();

        short8 aH[4], aL[4], bH[4], bL[4];
#pragma unroll
        for (int mi = 0; mi < 4; ++mi) {
            aH[mi] = *(const short8*)&AsH[(wr * 64 + mi * 16 + mrow) * 32 + kgrp];
            aL[mi] = *(const short8*)&AsL[(wr * 64 + mi * 16 + mrow) * 32 + kgrp];
        }
#pragma unroll
        for (int ni = 0; ni < 4; ++ni) {
            bH[ni] = *(const short8*)&BsH[(wc * 64 + ni * 16 + mrow) * 32 + kgrp];
            bL[ni] = *(const short8*)&BsL[(wc * 64 + ni * 16 + mrow) * 32 + kgrp];
        }
#pragma unroll
        for (int mi = 0; mi < 4; ++mi)
#pragma unroll
            for (int ni = 0; ni < 4; ++ni) {
                acc[mi][ni] = __builtin_amdgcn_mfma_f32_16x16x32_bf16(aH[mi], bH[ni], acc[mi][ni], 0, 0, 0);
                acc[mi][ni] = __builtin_amdgcn_mfma_f32_16x16x32_bf16(aL[mi], bH[ni], acc[mi][ni], 0, 0, 0);
                acc[mi][ni] = __builtin_amdgcn_mfma_f32_16x16x32_bf16(aH[mi], bL[ni], acc[mi][ni], 0, 0, 0);
            }
        __syncthreads();
    }

    const int crow = (lane >> 4) * 4;
#pragma unroll
    for (int mi = 0; mi < 4; ++mi)
#pragma unroll
        for (int ni = 0; ni < 4; ++ni)
#pragma unroll
            for (int j = 0; j < 4; ++j)
                C[(size_t)(row0 + wr * 64 + mi * 16 + crow + j) * N + col0 + wc * 64 + ni * 16 + mrow]
                    = acc[mi][ni][j];
}

// ---------------- correction GEMM: per stream z, ov[t',col] += r[t',:] @ P0T[col,:]^T
__global__ __launch_bounds__(256) void corr_gemm(
    const u16* __restrict__ Ah, const u16* __restrict__ Al,
    const u16* __restrict__ BTh, const u16* __restrict__ BTl,
    float* __restrict__ OV)
{
    __shared__ u16 AsH[128 * 32];
    __shared__ u16 AsL[128 * 32];
    __shared__ u16 BsH[128 * 32];
    __shared__ u16 BsL[128 * 32];
    const int tid = threadIdx.x;
    const int lane = tid & 63;
    const int w = tid >> 6;
    const int wr = w >> 1, wc = w & 1;
    const int row0 = blockIdx.y * 128;
    const int mrow = lane & 15;
    const int kgrp = (lane >> 4) * 8;

    const int bh = blockIdx.z;
    const int b = bh >> 3, h = bh & 7;
    const size_t aoff = (size_t)b * 2097152 + (size_t)h * 128;
    const size_t boff = (size_t)bh * 16384;
    const size_t coff = (size_t)b * 2097152 + (size_t)1048576 + (size_t)h * 128;

    f32x4 acc[4][4] = {};

    const int off0 = w * 1024 + lane * 16;
    const int r0 = off0 >> 6, kl0 = (off0 & 63) >> 1;
    const int off1 = off0 + 4096;
    const int r1 = off1 >> 6, kl1 = (off1 & 63) >> 1;

    for (int kt = 0; kt < 128; kt += 32) {
        GLOAD_LDS16(Ah  + aoff + (size_t)(row0 + r0) * 1024 + kt + kl0, (char*)AsH + w * 1024);
        GLOAD_LDS16(Ah  + aoff + (size_t)(row0 + r1) * 1024 + kt + kl1, (char*)AsH + w * 1024 + 4096);
        GLOAD_LDS16(Al  + aoff + (size_t)(row0 + r0) * 1024 + kt + kl0, (char*)AsL + w * 1024);
        GLOAD_LDS16(Al  + aoff + (size_t)(row0 + r1) * 1024 + kt + kl1, (char*)AsL + w * 1024 + 4096);
        GLOAD_LDS16(BTh + boff + (size_t)r0 * 128 + kt + kl0, (char*)BsH + w * 1024);
        GLOAD_LDS16(BTh + boff + (size_t)r1 * 128 + kt + kl1, (char*)BsH + w * 1024 + 4096);
        GLOAD_LDS16(BTl + boff + (size_t)r0 * 128 + kt + kl0, (char*)BsL + w * 1024);
        GLOAD_LDS16(BTl + boff + (size_t)r1 * 128 + kt + kl1, (char*)BsL + w * 1024 + 4096);
        __syncthreads();

        short8 aH[4], aL[4], bH[4], bL[4];
#pragma unroll
        for (int mi = 0; mi < 4; ++mi) {
            aH[mi] = *(const short8*)&AsH[(wr * 64 + mi * 16 + mrow) * 32 + kgrp];
            aL[mi] = *(const short8*)&AsL[(wr * 64 + mi * 16 + mrow) * 32 + kgrp];
        }
#pragma unroll
        for (int ni = 0; ni < 4; ++ni) {
            bH[ni] = *(const short8*)&BsH[(wc * 64 + ni * 16 + mrow) * 32 + kgrp];
            bL[ni] = *(const short8*)&BsL[(wc * 64 + ni * 16 + mrow) * 32 + kgrp];
        }
#pragma unroll
        for (int mi = 0; mi < 4; ++mi)
#pragma unroll
            for (int ni = 0; ni < 4; ++ni) {
                acc[mi][ni] = __builtin_amdgcn_mfma_f32_16x16x32_bf16(aH[mi], bH[ni], acc[mi][ni], 0, 0, 0);
                acc[mi][ni] = __builtin_amdgcn_mfma_f32_16x16x32_bf16(aL[mi], bH[ni], acc[mi][ni], 0, 0, 0);
                acc[mi][ni] = __builtin_amdgcn_mfma_f32_16x16x32_bf16(aH[mi], bL[ni], acc[mi][ni], 0, 0, 0);
            }
        __syncthreads();
    }

    const int crow = (lane >> 4) * 4;
#pragma unroll
    for (int mi = 0; mi < 4; ++mi)
#pragma unroll
        for (int ni = 0; ni < 4; ++ni)
#pragma unroll
            for (int j = 0; j < 4; ++j) {
                const size_t idx = coff + (size_t)(row0 + wr * 64 + mi * 16 + crow + j) * 1024
                                 + wc * 64 + ni * 16 + mrow;
                OV[idx] += acc[mi][ni][j];
            }
}

// ---------------- plain bf16 MFMA GEMM (final projection)
__global__ __launch_bounds__(256) void gemm_bf16(
    const u16* __restrict__ A, const u16* __restrict__ BT, float* __restrict__ C,
    int M, int N, int K)
{
    __shared__ u16 As[128 * 32];
    __shared__ u16 Bs[128 * 32];
    const int tid = threadIdx.x;
    const int lane = tid & 63;
    const int w = tid >> 6;
    const int wr = w >> 1, wc = w & 1;
    const int row0 = blockIdx.y * 128;
    const int col0 = blockIdx.x * 128;
    const int mrow = lane & 15;
    const int kgrp = (lane >> 4) * 8;

    f32x4 acc[4][4] = {};

    const int off0 = w * 1024 + lane * 16;
    const int r0 = off0 >> 6, kl0 = (off0 & 63) >> 1;
    const int off1 = off0 + 4096;
    const int r1 = off1 >> 6, kl1 = (off1 & 63) >> 1;

    for (int kt = 0; kt < K; kt += 32) {
        GLOAD_LDS16(A  + (size_t)(row0 + r0) * K + kt + kl0, (char*)As + w * 1024);
        GLOAD_LDS16(A  + (size_t)(row0 + r1) * K + kt + kl1, (char*)As + w * 1024 + 4096);
        GLOAD_LDS16(BT + (size_t)(col0 + r0) * K + kt + kl0, (char*)Bs + w * 1024);
        GLOAD_LDS16(BT + (size_t)(col0 + r1) * K + kt + kl1, (char*)Bs + w * 1024 + 4096);
        __syncthreads();

        short8 aF[4], bF[4];
#pragma unroll
        for (int mi = 0; mi < 4; ++mi)
            aF[mi] = *(const short8*)&As[(wr * 64 + mi * 16 + mrow) * 32 + kgrp];
#pragma unroll
        for (int ni = 0; ni < 4; ++ni)
            bF[ni] = *(const short8*)&Bs[(wc * 64 + ni * 16 + mrow) * 32 + kgrp];
#pragma unroll
        for (int mi = 0; mi < 4; ++mi)
#pragma unroll
            for (int ni = 0; ni < 4; ++ni)
                acc[mi][ni] = __builtin_amdgcn_mfma_f32_16x16x32_bf16(aF[mi], bF[ni], acc[mi][ni], 0, 0, 0);
        __syncthreads();
    }

    const int crow = (lane >> 4) * 4;
#pragma unroll
    for (int mi = 0; mi < 4; ++mi)
#pragma unroll
        for (int ni = 0; ni < 4; ++ni)
#pragma unroll
            for (int j = 0; j < 4; ++j)
                C[(size_t)(row0 + wr * 64 + mi * 16 + crow + j) * N + col0 + wc * 64 + ni * 16 + mrow]
                    = acc[mi][ni][j];
}

// ---------------- prep: block per (row,h), 128 thr. Plain record layout.
__global__ __launch_bounds__(128) void prep_kernel(
    const float* __restrict__ qkv, const float* __restrict__ fraw,
    const float* __restrict__ beta, float* __restrict__ sb)
{
    const int gid = blockIdx.x;
    const int h = gid & 7;
    const int row = gid >> 3;
    const int tid = threadIdx.x;
    const int col = h * 128 + tid;
    const size_t rb3 = (size_t)row * 3072;

    __shared__ float red[3][128];

    const float ksil = siluf(qkv[rb3 + 1024 + col]);
    red[0][tid] = ksil * ksil;
    __syncthreads();
    for (int off = 64; off > 0; off >>= 1) {
        if (tid < off) red[0][tid] += red[0][tid + off];
        __syncthreads();
    }
    const float rn = rsqrtf(red[0][0] + 1e-6f);
    __syncthreads();

    const float kn = ksil * rn;
    const float e  = sigmf(fraw[(size_t)row * 1024 + col]);
    const float qs = siluf(qkv[rb3 + col]);
    const float vs = siluf(qkv[rb3 + 2048 + col]);
    const float kev = e * kn;
    const float qev = e * qs;

    red[0][tid] = kev * kn;   // c
    red[1][tid] = qs * kev;   // d1
    red[2][tid] = qs * kn;    // d2
    __syncthreads();
    for (int off = 64; off > 0; off >>= 1) {
        if (tid < off) {
            red[0][tid] += red[0][tid + off];
            red[1][tid] += red[1][tid + off];
            red[2][tid] += red[2][tid + off];
        }
        __syncthreads();
    }

    float* o = sb + (size_t)gid * RECF;
    o[tid]        = kn;
    o[128 + tid]  = e;
    o[256 + tid]  = qev;
    o[384 + tid]  = vs;
    if (tid == 0) {
        o[512] = beta[(size_t)row * 8 + h];
        o[513] = red[0][0];
        o[514] = red[1][0];
        o[515] = red[2][0];
    }
}

// ---------------- scan
// 32-lane sum: 4 DPP stages (within 16) + ds_swizzle xor16 (within 32-groups).
__device__ __forceinline__ float red32(float x)
{
    x += __int_as_float(__builtin_amdgcn_mov_dpp(__float_as_int(x), 0xB1,  0xF, 0xF, true));
    x += __int_as_float(__builtin_amdgcn_mov_dpp(__float_as_int(x), 0x4E,  0xF, 0xF, true));
    x += __int_as_float(__builtin_amdgcn_mov_dpp(__float_as_int(x), 0x141, 0xF, 0xF, true));
    x += __int_as_float(__builtin_amdgcn_mov_dpp(__float_as_int(x), 0x140, 0xF, 0xF, true));
    x += __int_as_float(__builtin_amdgcn_ds_swizzle(__float_as_int(x), 0x401F));
    return x;
}

struct TR { float4 k, e, q, sc; float vc; };

__device__ __forceinline__ void ldtok(const char* __restrict__ rec, int rg, int cl, TR& T)
{
    T.k  = *(const float4*)(rec + rg * 16);
    T.e  = *(const float4*)(rec + 512 + rg * 16);
    T.q  = *(const float4*)(rec + 1024 + rg * 16);
    T.vc = *(const float*)(rec + 1536 + cl * 4);
    T.sc = *(const float4*)(rec + 1568);
}

#define STEP(T, SOFF)                                                              \
  {                                                                                \
    const float m0 = T.k.x * S0, m1 = T.k.y * S1, m2 = T.k.z * S2, m3 = T.k.w * S3; \
    float bS  = (m0 + m1) + (m2 + m3);                                             \
    float keS = (T.e.x * m0 + T.e.y * m1) + (T.e.z * m2 + T.e.w * m3);             \
    float qeS = (T.q.x * S0 + T.q.y * S1) + (T.q.z * S2 + T.q.w * S3);             \
    bS = red32(bS); keS = red32(keS); qeS = red32(qeS);                            \
    const float bSb = T.sc.x * bS;                                                 \
    const float ks  = keS - bSb * T.sc.y;                                          \
    const float wv  = T.vc - T.sc.x * ks;                                          \
    const float o   = (qeS - bSb * T.sc.z) + wv * T.sc.w;                          \
    S0 = T.e.x * (S0 - bSb * T.k.x) + wv * T.k.x;                                  \
    S1 = T.e.y * (S1 - bSb * T.k.y) + wv * T.k.y;                                  \
    S2 = T.e.z * (S2 - bSb * T.k.z) + wv * T.k.z;                                  \
    S3 = T.e.w * (S3 - bSb * T.k.w) + wv * T.k.w;                                  \
    if (rg == 0) {                                                                 \
        if (basis) {                                                               \
            u16 hi, lo; splitbf(o, hi, lo);                                        \
            rbh[oidx + (size_t)(SOFF) * 1024] = hi;                                \
            rbl[oidx + (size_t)(SOFF) * 1024] = lo;                                \
        } else {                                                                   \
            ov[oidx + (size_t)(SOFF) * 1024] = o;                                  \
        }                                                                          \
    }                                                                              \
  }

#define SBAR __builtin_amdgcn_sched_barrier(0)

__device__ __forceinline__ void stage_batch(
    const float* __restrict__ p0, char* ldsbuf, int t0, int w, int lane, int vg)
{
    for (int s = w; s < TOKB; s += 4) {
        const char* src = (const char*)(p0 + (size_t)(t0 + s) * RECSTRIDE);
        char* dst = ldsbuf + s * SLOTB;
        GLOAD_LDS16(src + lane * 16, dst);                               // k,e (1024B)
        if (lane < 32) GLOAD_LDS16(src + 1024 + lane * 16, dst + 1024);  // qe (512B)
        if (lane < 2)  GLOAD_LDS16(src + 1536 + vg * 32 + lane * 16, dst + 1536); // v slice
        if (lane == 0) GLOAD_LDS16(src + 2048, dst + 1568);              // sc
    }
}

// 768 blocks x 256 threads (3072 waves = 3/SIMD, 3 blocks/CU @ 50KB LDS).
// bh = blk&15 keeps a stream on one XCD. gidx = blk>>4 in [0,48):
//   gidx<16 -> chunk0 (t 0..1023), real cols gidx*8.., emits P0^T bf16.
//   else    -> chunk1 (t 1024..2047), cg2 = gidx-16 in [0,32):
//              colx = cg2*8+cl; colx<128 real (corrected later), >=128 basis
//              (S0=I, v=0) -> r_t emitted bf16 hi/lo directly.
__global__ __launch_bounds__(256) void scan_kernel(
    const float* __restrict__ sb, float* __restrict__ ov,
    u16* __restrict__ rbh, u16* __restrict__ rbl,
    u16* __restrict__ pTh, u16* __restrict__ pTl)
{
    __shared__ char lds[2 * TOKB * SLOTB];   // 51200 B

    const int tid = threadIdx.x;
    const int blk = blockIdx.x;
    const int cl = tid >> 5;      // 0..7
    const int rg = tid & 31;
    const int w = tid >> 6;
    const int lane = tid & 63;

    const int bh = blk & 15;
    const int gidx = blk >> 4;

    int vg, tstart, colx;
    bool chunk0, basis = false;
    if (gidx < 16) {
        colx = gidx * 8 + cl; vg = gidx; tstart = 0; chunk0 = true;
    } else {
        const int cg2 = gidx - 16;
        colx = cg2 * 8 + cl; vg = cg2 & 15; tstart = 1024; chunk0 = false;
        basis = colx >= 128;
    }
    const int b = bh >> 3, h = bh & 7;
    const size_t base = (size_t)b * 2048 * 8 + h;
    const float* p0 = sb + base * RECF + (size_t)tstart * RECSTRIDE;

    size_t oidx;
    if (chunk0)      oidx = base * 128 + colx;
    else if (!basis) oidx = base * 128 + (size_t)1048576 + colx;
    else             oidx = base * 128 + (colx - 128);

    const float vmask = basis ? 0.f : 1.f;
    float S0, S1, S2, S3;
    if (basis) {
        const int jb = colx - 128;
        S0 = (rg * 4 + 0 == jb) ? 1.f : 0.f;
        S1 = (rg * 4 + 1 == jb) ? 1.f : 0.f;
        S2 = (rg * 4 + 2 == jb) ? 1.f : 0.f;
        S3 = (rg * 4 + 3 == jb) ? 1.f : 0.f;
    } else { S0 = S1 = S2 = S3 = 0.f; }

    stage_batch(p0, lds, 0, w, lane, vg);
    __syncthreads();

    int cur = 0;
    for (int t0 = 0; t0 < 1024; t0 += TOKB) {
        if (t0 + TOKB < 1024)
            stage_batch(p0, lds + (cur ^ 1) * (TOKB * SLOTB), t0 + TOKB, w, lane, vg);

        const char* bufp = lds + cur * (TOKB * SLOTB);
        TR A, B;
        ldtok(bufp, rg, cl, A); A.vc *= vmask; SBAR;
#pragma unroll
        for (int s = 0; s < TOKB; s += 2) {
            ldtok(bufp + (s + 1) * SLOTB, rg, cl, B); B.vc *= vmask; SBAR;
            STEP(A, s);
            if (s + 2 < TOKB) { ldtok(bufp + (s + 2) * SLOTB, rg, cl, A); A.vc *= vmask; SBAR; }
            STEP(B, s + 1);
        }
        __syncthreads();
        cur ^= 1;
        oidx += (size_t)TOKB * 1024;
    }

    if (chunk0) {
        // emit P0^T ([col][row]) as bf16 hi/lo directly
        u16 h0, l0, h1, l1, h2, l2, h3, l3;
        splitbf(S0, h0, l0); splitbf(S1, h1, l1);
        splitbf(S2, h2, l2); splitbf(S3, h3, l3);
        const size_t po = (size_t)bh * 16384 + (size_t)colx * 128 + rg * 4;
        su4 hv = {(short)h0, (short)h1, (short)h2, (short)h3};
        su4 lv = {(short)l0, (short)l1, (short)l2, (short)l3};
        *(su4*)(pTh + po) = hv;
        *(su4*)(pTl + po) = lv;
    }
}

// ---------------- post: y = o*sigmoid(gate); per-head RMS; *norm_w -> bf16
__global__ __launch_bounds__(128) void post_kernel(
    const float* __restrict__ ov, const float* __restrict__ gate,
    const float* __restrict__ normw, u16* __restrict__ ybf)
{
    const int gid = blockIdx.x;
    const int h = gid & 7;
    const int row = gid >> 3;
    const int tid = threadIdx.x;
    const int col = h * 128 + tid;

    __shared__ float red[128];

    const float o = ov[(size_t)row * 1024 + col];
    const float y = o * sigmf(gate[(size_t)row * 1024 + col]);

    red[tid] = y * y;
    __syncthreads();
    for (int off = 64; off > 0; off >>= 1) {
        if (tid < off) red[tid] += red[tid + off];
        __syncthreads();
    }
    const float rms = rsqrtf(red[0] * (1.f / 128.f) + 1e-6f);
    ybf[(size_t)row * 1024 + col] = f2bf(y * rms * normw[col]);
}

extern "C" void kernel_launch(void* const* d_in, const int* in_sizes, int n_in,
                              void* d_out, int out_size, void* d_ws, size_t ws_size,
                              hipStream_t stream)
{
    const float* x     = (const float*)d_in[0];
    const float* Wq    = (const float*)d_in[1];
    const float* Wk    = (const float*)d_in[2];
    const float* Wv    = (const float*)d_in[3];
    const float* Wf1   = (const float*)d_in[4];
    const float* Wf2   = (const float*)d_in[5];
    const float* Wbeta = (const float*)d_in[6];
    const float* Wog1  = (const float*)d_in[7];
    const float* Wog2  = (const float*)d_in[8];
    const float* normw = (const float*)d_in[9];
    const float* Wo    = (const float*)d_in[10];
    float* out = (float*)d_out;

    float* ws    = (float*)d_ws;
    float* qkv   = ws;                                 // 12M f [4096x3072]
    float* sb    = qkv + 3 * SZT;                      // 17.04M f
    float* ovr   = sb + (size_t)32768 * RECF;          // 4M f (early: Wqkv splits; then fraw; then ov)
    float* rbspace = ovr + SZT;                        // 4M f -> rbh/rbl u16
    float* pbspace = rbspace + SZT;                    // 256K f -> pTh/pTl u16
    float* wot   = pbspace + 262144;                   // 0.5M f
    float* wcatT = wot + 524288;                       // 0.25M f
    float* wfog  = wcatT + 262144;                     // 0.25M f
    float* f1sp  = wfog + 262144;                      // 1M f
    float* betap = f1sp + 1048576;                     // 32K f
    float* xsp   = betap + 32768;                      // 4M f (xh/xl)

    // early buffer inside sb (dead before prep writes sb)
    float* f1og = sb;                                  // 1M f

    u16* WqkvTh = (u16*)ovr;                           // 3M u16
    u16* WqkvTl = WqkvTh + (size_t)3 * 1024 * 1024;    // 3M u16
    float* fraw = ovr;                                 // after qkv gemm

    u16* xh  = (u16*)xsp;
    u16* xl  = xh + SZT;

    u16* rbh = (u16*)rbspace;
    u16* rbl = rbh + SZT;
    u16* pTh = (u16*)pbspace;
    u16* pTl = pTh + 262144;

    u16* WoT    = (u16*)wot;
    u16* WcatTh = (u16*)wcatT;
    u16* WcatTl = WcatTh + (size_t)256 * 1024;
    u16* Wf2Th  = (u16*)wfog;
    u16* Wf2Tl  = Wf2Th + (size_t)1024 * 128;
    u16* Wog2Th = Wf2Tl + (size_t)1024 * 128;
    u16* Wog2Tl = Wog2Th + (size_t)1024 * 128;
    u16* f1ogh  = (u16*)f1sp;
    u16* f1ogl  = f1ogh + (size_t)4096 * 256;

    float* gate = qkv;                                 // qkv dead after prep
    u16*   ybf  = (u16*)(qkv + SZT);

    dim3 b256(256), b128(128);

    wtrans_split_qkv<<<dim3(32, 32, 3), b256, 0, stream>>>(Wq, Wk, Wv, WqkvTh, WqkvTl);
    wtrans<<<dim3(32, 32), b256, 0, stream>>>(Wo, WoT);
    conv_split<<<2048, b256, 0, stream>>>(x, xh, xl);
    wtrans_split4<<<dim3(128, 1, 4), b256, 0, stream>>>(
        Wf1, Wog1, Wf2, Wog2, WcatTh, WcatTl, Wf2Th, Wf2Tl, Wog2Th, Wog2Tl);
    beta_kernel<<<4096, b256, 0, stream>>>(x, Wbeta, betap);

    gemm_bf16_split<<<dim3(24, 32), b256, 0, stream>>>(xh, xl, WqkvTh, WqkvTl, qkv, 4096, 3072, 1024, 1024, 1024);
    gemm_bf16_split<<<dim3(2, 32), b256, 0, stream>>>(xh, xl, WcatTh, WcatTl, f1og, 4096, 256, 1024, 1024, 1024);
    conv_split<<<512, b256, 0, stream>>>(f1og, f1ogh, f1ogl);
    gemm_bf16_split<<<dim3(8, 32), b256, 0, stream>>>(f1ogh, f1ogl, Wf2Th, Wf2Tl, fraw, 4096, 1024, 128, 256, 128);

    prep_kernel<<<32768, b128, 0, stream>>>(qkv, fraw, betap, sb);
    gemm_bf16_split<<<dim3(8, 32), b256, 0, stream>>>(f1ogh + 128, f1ogl + 128, Wog2Th, Wog2Tl, gate, 4096, 1024, 128, 256, 128);

    scan_kernel<<<768, b256, 0, stream>>>(sb, ovr, rbh, rbl, pTh, pTl);

    corr_gemm<<<dim3(1, 8, 16), b256, 0, stream>>>(rbh, rbl, pTh, pTl, ovr);

    post_kernel<<<32768, b128, 0, stream>>>(ovr, gate, normw, ybf);

    gemm_bf16<<<dim3(8, 32), b256, 0, stream>>>(ybf, WoT, out, 4096, 1024, 1024);
}

// Round 16
// 669.958 us; speedup vs baseline: 1.1528x; 1.0887x over previous
//
#include <hip/hip_runtime.h>
#include <cmath>

// DenseRnn on MI355X. B=2, N=2048, D=1024, H=8, HD=128.
//
//  wtrans_split_qkv (z=3): Wq/Wk/Wv -> bf16 hi/lo transposed (one launch)
//  wtrans_split4 (z=4): Wf1,Wog1 -> WcatT; Wf2,Wog2 -> T
//  wtrans: Wo plain bf16; conv_split: x -> bf16 hi/lo
//  gemm_bf16_split: qkv = x@[Wq|Wk|Wv]; f1og = x@Wcat; fraw = f1@Wf2; gate = og1@Wog2
//  beta_kernel; prep -> records sb[520] = {k,e,qe,v, sc@512}
//  scan (C=2, R12 geometry): 32 lanes/col x 4 rows/lane, 768 x 256-thr blocks.
//    R15 post-mortem: inline-asm v_add_f32_dpp hit the VALU->DPP-read hazard
//    (compiler can't insert the 2 required wait states inside asm) -> corrupt.
//    This round: builtin mov_dpp reduction (hazard-safe) + packed-f32 STEP.
//  corr_gemm: ov[chunk1] += r @ P0 (per-stream MFMA)
//  post: y = o*sigmoid(gate), per-head RMS, *norm_w -> bf16
//  gemm_bf16: y@Wo -> out

#define SZT ((size_t)4096 * 1024)
#define RECF 520
#define RECSTRIDE 4160     // 8*RECF floats between consecutive tokens of a stream
#define TOKB 16
#define SLOTB 1600         // k 512 | e 512 | qe 512 | v 32 | sc 16 | pad

typedef unsigned short u16;
typedef __attribute__((ext_vector_type(8))) short short8;
typedef __attribute__((ext_vector_type(4))) short su4;
typedef __attribute__((ext_vector_type(4))) float f32x4;
typedef __attribute__((ext_vector_type(2))) float f2;

__device__ __forceinline__ float sigmf(float x) { return 1.f / (1.f + expf(-x)); }
__device__ __forceinline__ float siluf(float x) { return x * sigmf(x); }
__device__ __forceinline__ u16 f2bf(float f) {
    unsigned int u = __float_as_uint(f);
    unsigned int r = (u + 0x7FFFu + ((u >> 16) & 1u)) >> 16;
    return (u16)r;
}
__device__ __forceinline__ float bf2f(u16 h) { return __uint_as_float((unsigned int)h << 16); }
__device__ __forceinline__ void splitbf(float f, u16& hi, u16& lo) {
    hi = f2bf(f);
    lo = f2bf(f - bf2f(hi));
}

#define GLOAD_LDS16(gp, lp) __builtin_amdgcn_global_load_lds( \
    (const __attribute__((address_space(1))) void*)(gp),      \
    (__attribute__((address_space(3))) void*)(lp), 16, 0, 0)

// ---------------- transpose+split body (32x32 tile)
__device__ __forceinline__ void wtrans_split_body(
    const float* __restrict__ W, u16* __restrict__ WTh, u16* __restrict__ WTl,
    int K, int N, int bx, int by)
{
    __shared__ float t[32][33];
    const int tx = threadIdx.x & 31, ty = threadIdx.x >> 5;
    const int n0 = bx * 32, k0 = by * 32;
#pragma unroll
    for (int i = 0; i < 4; i++)
        t[ty + i * 8][tx] = W[(size_t)(k0 + ty + i * 8) * N + n0 + tx];
    __syncthreads();
#pragma unroll
    for (int i = 0; i < 4; i++) {
        u16 hi, lo;
        splitbf(t[tx][ty + i * 8], hi, lo);
        WTh[(size_t)(n0 + ty + i * 8) * K + k0 + tx] = hi;
        WTl[(size_t)(n0 + ty + i * 8) * K + k0 + tx] = lo;
    }
}

__global__ __launch_bounds__(256) void wtrans_split_qkv(
    const float* __restrict__ Wq, const float* __restrict__ Wk, const float* __restrict__ Wv,
    u16* __restrict__ WTh, u16* __restrict__ WTl)
{
    const int z = blockIdx.z;
    const float* W = (z == 0) ? Wq : (z == 1) ? Wk : Wv;
    wtrans_split_body(W, WTh + (size_t)z * 1024 * 1024, WTl + (size_t)z * 1024 * 1024,
                      1024, 1024, blockIdx.x, blockIdx.y);
}

__global__ __launch_bounds__(256) void wtrans_split4(
    const float* __restrict__ Wf1, const float* __restrict__ Wog1,
    const float* __restrict__ Wf2, const float* __restrict__ Wog2,
    u16* __restrict__ WcatTh, u16* __restrict__ WcatTl,
    u16* __restrict__ Wf2Th, u16* __restrict__ Wf2Tl,
    u16* __restrict__ Wog2Th, u16* __restrict__ Wog2Tl)
{
    const int z = blockIdx.z;
    const float* W; u16 *Th, *Tl; int K, N;
    if (z == 0)      { W = Wf1;  Th = WcatTh; Tl = WcatTl; K = 1024; N = 128; }
    else if (z == 1) { W = Wog1; Th = WcatTh + (size_t)128 * 1024; Tl = WcatTl + (size_t)128 * 1024; K = 1024; N = 128; }
    else if (z == 2) { W = Wf2;  Th = Wf2Th;  Tl = Wf2Tl;  K = 128; N = 1024; }
    else             { W = Wog2; Th = Wog2Th; Tl = Wog2Tl; K = 128; N = 1024; }
    const int nbx = N / 32;
    wtrans_split_body(W, Th, Tl, K, N, blockIdx.x % nbx, blockIdx.x / nbx);
}

__global__ __launch_bounds__(256) void wtrans(const float* __restrict__ W, u16* __restrict__ WT)
{
    __shared__ float t[32][33];
    const int tx = threadIdx.x & 31, ty = threadIdx.x >> 5;
    const int n0 = blockIdx.x * 32, k0 = blockIdx.y * 32;
#pragma unroll
    for (int i = 0; i < 4; i++)
        t[ty + i * 8][tx] = W[(size_t)(k0 + ty + i * 8) * 1024 + n0 + tx];
    __syncthreads();
#pragma unroll
    for (int i = 0; i < 4; i++)
        WT[(size_t)(n0 + ty + i * 8) * 1024 + k0 + tx] = f2bf(t[tx][ty + i * 8]);
}

__global__ __launch_bounds__(256) void conv_split(
    const float* __restrict__ in, u16* __restrict__ oh, u16* __restrict__ ol)
{
    const size_t i = ((size_t)blockIdx.x * 256 + threadIdx.x) * 8;
    short8 rh, rl;
#pragma unroll
    for (int j = 0; j < 8; j++) {
        u16 hi, lo;
        splitbf(in[i + j], hi, lo);
        rh[j] = (short)hi; rl[j] = (short)lo;
    }
    *(short8*)&oh[i] = rh;
    *(short8*)&ol[i] = rl;
}

__global__ __launch_bounds__(256) void beta_kernel(
    const float* __restrict__ x, const float* __restrict__ Wbeta, float* __restrict__ beta)
{
    const int row = blockIdx.x;
    const int tid = threadIdx.x;
    const int lane = tid & 63, wid = tid >> 6;
    __shared__ float wsum[4][8];
    float4 xv = *(const float4*)&x[(size_t)row * 1024 + tid * 4];
    float p[8];
#pragma unroll
    for (int h = 0; h < 8; h++)
        p[h] = xv.x * Wbeta[(size_t)(tid * 4 + 0) * 8 + h]
             + xv.y * Wbeta[(size_t)(tid * 4 + 1) * 8 + h]
             + xv.z * Wbeta[(size_t)(tid * 4 + 2) * 8 + h]
             + xv.w * Wbeta[(size_t)(tid * 4 + 3) * 8 + h];
#pragma unroll
    for (int off = 32; off >= 1; off >>= 1)
#pragma unroll
        for (int h = 0; h < 8; h++) p[h] += __shfl_xor(p[h], off);
    if (lane == 0)
#pragma unroll
        for (int h = 0; h < 8; h++) wsum[wid][h] = p[h];
    __syncthreads();
    if (tid < 8) {
        float s = wsum[0][tid] + wsum[1][tid] + wsum[2][tid] + wsum[3][tid];
        beta[(size_t)row * 8 + tid] = 2.f * sigmf(s);
    }
}

// ---------------- split bf16 MFMA GEMM
__global__ __launch_bounds__(256) void gemm_bf16_split(
    const u16* __restrict__ Ah, const u16* __restrict__ Al,
    const u16* __restrict__ BTh, const u16* __restrict__ BTl,
    float* __restrict__ C, int M, int N, int K, int lda, int ldb)
{
    __shared__ u16 AsH[128 * 32];
    __shared__ u16 AsL[128 * 32];
    __shared__ u16 BsH[128 * 32];
    __shared__ u16 BsL[128 * 32];
    const int tid = threadIdx.x;
    const int lane = tid & 63;
    const int w = tid >> 6;
    const int wr = w >> 1, wc = w & 1;
    const int row0 = blockIdx.y * 128;
    const int col0 = blockIdx.x * 128;
    const int mrow = lane & 15;
    const int kgrp = (lane >> 4) * 8;

    f32x4 acc[4][4] = {};

    const int off0 = w * 1024 + lane * 16;
    const int r0 = off0 >> 6, kl0 = (off0 & 63) >> 1;
    const int off1 = off0 + 4096;
    const int r1 = off1 >> 6, kl1 = (off1 & 63) >> 1;

    for (int kt = 0; kt < K; kt += 32) {
        GLOAD_LDS16(Ah  + (size_t)(row0 + r0) * lda + kt + kl0, (char*)AsH + w * 1024);
        GLOAD_LDS16(Ah  + (size_t)(row0 + r1) * lda + kt + kl1, (char*)AsH + w * 1024 + 4096);
        GLOAD_LDS16(Al  + (size_t)(row0 + r0) * lda + kt + kl0, (char*)AsL + w * 1024);
        GLOAD_LDS16(Al  + (size_t)(row0 + r1) * lda + kt + kl1, (char*)AsL + w * 1024 + 4096);
        GLOAD_LDS16(BTh + (size_t)(col0 + r0) * ldb + kt + kl0, (char*)BsH + w * 1024);
        GLOAD_LDS16(BTh + (size_t)(col0 + r1) * ldb + kt + kl1, (char*)BsH + w * 1024 + 4096);
        GLOAD_LDS16(BTl + (size_t)(col0 + r0) * ldb + kt + kl0, (char*)BsL + w * 1024);
        GLOAD_LDS16(BTl + (size_t)(col0 + r1) * ldb + kt + kl1, (char*)BsL + w * 1024 + 4096);
        __syncthreads();

        short8 aH[4], aL[4], bH[4], bL[4];
#pragma unroll
        for (int mi = 0; mi < 4; ++mi) {
            aH[mi] = *(const short8*)&AsH[(wr * 64 + mi * 16 + mrow) * 32 + kgrp];
            aL[mi] = *(const short8*)&AsL[(wr * 64 + mi * 16 + mrow) * 32 + kgrp];
        }
#pragma unroll
        for (int ni = 0; ni < 4; ++ni) {
            bH[ni] = *(const short8*)&BsH[(wc * 64 + ni * 16 + mrow) * 32 + kgrp];
            bL[ni] = *(const short8*)&BsL[(wc * 64 + ni * 16 + mrow) * 32 + kgrp];
        }
#pragma unroll
        for (int mi = 0; mi < 4; ++mi)
#pragma unroll
            for (int ni = 0; ni < 4; ++ni) {
                acc[mi][ni] = __builtin_amdgcn_mfma_f32_16x16x32_bf16(aH[mi], bH[ni], acc[mi][ni], 0, 0, 0);
                acc[mi][ni] = __builtin_amdgcn_mfma_f32_16x16x32_bf16(aL[mi], bH[ni], acc[mi][ni], 0, 0, 0);
                acc[mi][ni] = __builtin_amdgcn_mfma_f32_16x16x32_bf16(aH[mi], bL[ni], acc[mi][ni], 0, 0, 0);
            }
        __syncthreads();
    }

    const int crow = (lane >> 4) * 4;
#pragma unroll
    for (int mi = 0; mi < 4; ++mi)
#pragma unroll
        for (int ni = 0; ni < 4; ++ni)
#pragma unroll
            for (int j = 0; j < 4; ++j)
                C[(size_t)(row0 + wr * 64 + mi * 16 + crow + j) * N + col0 + wc * 64 + ni * 16 + mrow]
                    = acc[mi][ni][j];
}

// ---------------- correction GEMM: per stream z, ov[t',col] += r[t',:] @ P0T[col,:]^T
__global__ __launch_bounds__(256) void corr_gemm(
    const u16* __restrict__ Ah, const u16* __restrict__ Al,
    const u16* __restrict__ BTh, const u16* __restrict__ BTl,
    float* __restrict__ OV)
{
    __shared__ u16 AsH[128 * 32];
    __shared__ u16 AsL[128 * 32];
    __shared__ u16 BsH[128 * 32];
    __shared__ u16 BsL[128 * 32];
    const int tid = threadIdx.x;
    const int lane = tid & 63;
    const int w = tid >> 6;
    const int wr = w >> 1, wc = w & 1;
    const int row0 = blockIdx.y * 128;
    const int mrow = lane & 15;
    const int kgrp = (lane >> 4) * 8;

    const int bh = blockIdx.z;
    const int b = bh >> 3, h = bh & 7;
    const size_t aoff = (size_t)b * 2097152 + (size_t)h * 128;
    const size_t boff = (size_t)bh * 16384;
    const size_t coff = (size_t)b * 2097152 + (size_t)1048576 + (size_t)h * 128;

    f32x4 acc[4][4] = {};

    const int off0 = w * 1024 + lane * 16;
    const int r0 = off0 >> 6, kl0 = (off0 & 63) >> 1;
    const int off1 = off0 + 4096;
    const int r1 = off1 >> 6, kl1 = (off1 & 63) >> 1;

    for (int kt = 0; kt < 128; kt += 32) {
        GLOAD_LDS16(Ah  + aoff + (size_t)(row0 + r0) * 1024 + kt + kl0, (char*)AsH + w * 1024);
        GLOAD_LDS16(Ah  + aoff + (size_t)(row0 + r1) * 1024 + kt + kl1, (char*)AsH + w * 1024 + 4096);
        GLOAD_LDS16(Al  + aoff + (size_t)(row0 + r0) * 1024 + kt + kl0, (char*)AsL + w * 1024);
        GLOAD_LDS16(Al  + aoff + (size_t)(row0 + r1) * 1024 + kt + kl1, (char*)AsL + w * 1024 + 4096);
        GLOAD_LDS16(BTh + boff + (size_t)r0 * 128 + kt + kl0, (char*)BsH + w * 1024);
        GLOAD_LDS16(BTh + boff + (size_t)r1 * 128 + kt + kl1, (char*)BsH + w * 1024 + 4096);
        GLOAD_LDS16(BTl + boff + (size_t)r0 * 128 + kt + kl0, (char*)BsL + w * 1024);
        GLOAD_LDS16(BTl + boff + (size_t)r1 * 128 + kt + kl1, (char*)BsL + w * 1024 + 4096);
        __syncthreads();

        short8 aH[4], aL[4], bH[4], bL[4];
#pragma unroll
        for (int mi = 0; mi < 4; ++mi) {
            aH[mi] = *(const short8*)&AsH[(wr * 64 + mi * 16 + mrow) * 32 + kgrp];
            aL[mi] = *(const short8*)&AsL[(wr * 64 + mi * 16 + mrow) * 32 + kgrp];
        }
#pragma unroll
        for (int ni = 0; ni < 4; ++ni) {
            bH[ni] = *(const short8*)&BsH[(wc * 64 + ni * 16 + mrow) * 32 + kgrp];
            bL[ni] = *(const short8*)&BsL[(wc * 64 + ni * 16 + mrow) * 32 + kgrp];
        }
#pragma unroll
        for (int mi = 0; mi < 4; ++mi)
#pragma unroll
            for (int ni = 0; ni < 4; ++ni) {
                acc[mi][ni] = __builtin_amdgcn_mfma_f32_16x16x32_bf16(aH[mi], bH[ni], acc[mi][ni], 0, 0, 0);
                acc[mi][ni] = __builtin_amdgcn_mfma_f32_16x16x32_bf16(aL[mi], bH[ni], acc[mi][ni], 0, 0, 0);
                acc[mi][ni] = __builtin_amdgcn_mfma_f32_16x16x32_bf16(aH[mi], bL[ni], acc[mi][ni], 0, 0, 0);
            }
        __syncthreads();
    }

    const int crow = (lane >> 4) * 4;
#pragma unroll
    for (int mi = 0; mi < 4; ++mi)
#pragma unroll
        for (int ni = 0; ni < 4; ++ni)
#pragma unroll
            for (int j = 0; j < 4; ++j) {
                const size_t idx = coff + (size_t)(row0 + wr * 64 + mi * 16 + crow + j) * 1024
                                 + wc * 64 + ni * 16 + mrow;
                OV[idx] += acc[mi][ni][j];
            }
}

// ---------------- plain bf16 MFMA GEMM (final projection)
__global__ __launch_bounds__(256) void gemm_bf16(
    const u16* __restrict__ A, const u16* __restrict__ BT, float* __restrict__ C,
    int M, int N, int K)
{
    __shared__ u16 As[128 * 32];
    __shared__ u16 Bs[128 * 32];
    const int tid = threadIdx.x;
    const int lane = tid & 63;
    const int w = tid >> 6;
    const int wr = w >> 1, wc = w & 1;
    const int row0 = blockIdx.y * 128;
    const int col0 = blockIdx.x * 128;
    const int mrow = lane & 15;
    const int kgrp = (lane >> 4) * 8;

    f32x4 acc[4][4] = {};

    const int off0 = w * 1024 + lane * 16;
    const int r0 = off0 >> 6, kl0 = (off0 & 63) >> 1;
    const int off1 = off0 + 4096;
    const int r1 = off1 >> 6, kl1 = (off1 & 63) >> 1;

    for (int kt = 0; kt < K; kt += 32) {
        GLOAD_LDS16(A  + (size_t)(row0 + r0) * K + kt + kl0, (char*)As + w * 1024);
        GLOAD_LDS16(A  + (size_t)(row0 + r1) * K + kt + kl1, (char*)As + w * 1024 + 4096);
        GLOAD_LDS16(BT + (size_t)(col0 + r0) * K + kt + kl0, (char*)Bs + w * 1024);
        GLOAD_LDS16(BT + (size_t)(col0 + r1) * K + kt + kl1, (char*)Bs + w * 1024 + 4096);
        __syncthreads();

        short8 aF[4], bF[4];
#pragma unroll
        for (int mi = 0; mi < 4; ++mi)
            aF[mi] = *(const short8*)&As[(wr * 64 + mi * 16 + mrow) * 32 + kgrp];
#pragma unroll
        for (int ni = 0; ni < 4; ++ni)
            bF[ni] = *(const short8*)&Bs[(wc * 64 + ni * 16 + mrow) * 32 + kgrp];
#pragma unroll
        for (int mi = 0; mi < 4; ++mi)
#pragma unroll
            for (int ni = 0; ni < 4; ++ni)
                acc[mi][ni] = __builtin_amdgcn_mfma_f32_16x16x32_bf16(aF[mi], bF[ni], acc[mi][ni], 0, 0, 0);
        __syncthreads();
    }

    const int crow = (lane >> 4) * 4;
#pragma unroll
    for (int mi = 0; mi < 4; ++mi)
#pragma unroll
        for (int ni = 0; ni < 4; ++ni)
#pragma unroll
            for (int j = 0; j < 4; ++j)
                C[(size_t)(row0 + wr * 64 + mi * 16 + crow + j) * N + col0 + wc * 64 + ni * 16 + mrow]
                    = acc[mi][ni][j];
}

// ---------------- prep
__global__ __launch_bounds__(128) void prep_kernel(
    const float* __restrict__ qkv, const float* __restrict__ fraw,
    const float* __restrict__ beta, float* __restrict__ sb)
{
    const int gid = blockIdx.x;
    const int h = gid & 7;
    const int row = gid >> 3;
    const int tid = threadIdx.x;
    const int col = h * 128 + tid;
    const size_t rb3 = (size_t)row * 3072;

    __shared__ float red[3][128];

    const float ksil = siluf(qkv[rb3 + 1024 + col]);
    red[0][tid] = ksil * ksil;
    __syncthreads();
    for (int off = 64; off > 0; off >>= 1) {
        if (tid < off) red[0][tid] += red[0][tid + off];
        __syncthreads();
    }
    const float rn = rsqrtf(red[0][0] + 1e-6f);
    __syncthreads();

    const float kn = ksil * rn;
    const float e  = sigmf(fraw[(size_t)row * 1024 + col]);
    const float qs = siluf(qkv[rb3 + col]);
    const float vs = siluf(qkv[rb3 + 2048 + col]);
    const float kev = e * kn;
    const float qev = e * qs;

    red[0][tid] = kev * kn;   // c
    red[1][tid] = qs * kev;   // d1
    red[2][tid] = qs * kn;    // d2
    __syncthreads();
    for (int off = 64; off > 0; off >>= 1) {
        if (tid < off) {
            red[0][tid] += red[0][tid + off];
            red[1][tid] += red[1][tid + off];
            red[2][tid] += red[2][tid + off];
        }
        __syncthreads();
    }

    float* o = sb + (size_t)gid * RECF;
    o[tid]        = kn;
    o[128 + tid]  = e;
    o[256 + tid]  = qev;
    o[384 + tid]  = vs;
    if (tid == 0) {
        o[512] = beta[(size_t)row * 8 + h];
        o[513] = red[0][0];
        o[514] = red[1][0];
        o[515] = red[2][0];
    }
}

// ---------------- scan
// 32-lane sum: 4 DPP stages (builtins: compiler handles the VALU->DPP-read
// hazard wait states) + ds_swizzle xor16.
__device__ __forceinline__ float red32(float x)
{
    x += __int_as_float(__builtin_amdgcn_mov_dpp(__float_as_int(x), 0xB1,  0xF, 0xF, true));
    x += __int_as_float(__builtin_amdgcn_mov_dpp(__float_as_int(x), 0x4E,  0xF, 0xF, true));
    x += __int_as_float(__builtin_amdgcn_mov_dpp(__float_as_int(x), 0x141, 0xF, 0xF, true));
    x += __int_as_float(__builtin_amdgcn_mov_dpp(__float_as_int(x), 0x140, 0xF, 0xF, true));
    x += __int_as_float(__builtin_amdgcn_ds_swizzle(__float_as_int(x), 0x401F));
    return x;
}

struct TR { float4 k, e, q, sc; float vc; };

__device__ __forceinline__ void ldtok(const char* __restrict__ rec, int rg, int cl, TR& T)
{
    T.k  = *(const float4*)(rec + rg * 16);
    T.e  = *(const float4*)(rec + 512 + rg * 16);
    T.q  = *(const float4*)(rec + 1024 + rg * 16);
    T.vc = *(const float*)(rec + 1536 + cl * 4);
    T.sc = *(const float4*)(rec + 1568);
}

// Packed-f32 step: float2 pairs -> v_pk_mul/pk_fma where the compiler can.
#define STEP(T, SOFF)                                                              \
  {                                                                                \
    const f2 k01 = *(const f2*)&T.k.x; const f2 k23 = *(const f2*)&T.k.z;          \
    const f2 e01 = *(const f2*)&T.e.x; const f2 e23 = *(const f2*)&T.e.z;          \
    const f2 q01 = *(const f2*)&T.q.x; const f2 q23 = *(const f2*)&T.q.z;          \
    const f2 m01 = k01 * s01, m23 = k23 * s23;                                     \
    const f2 bS2 = m01 + m23;                                                      \
    const f2 em2 = e01 * m01 + e23 * m23;                                          \
    const f2 qs2 = q01 * s01 + q23 * s23;                                          \
    float bS  = bS2.x + bS2.y;                                                     \
    float keS = em2.x + em2.y;                                                     \
    float qeS = qs2.x + qs2.y;                                                     \
    bS = red32(bS); keS = red32(keS); qeS = red32(qeS);                            \
    const float bSb = T.sc.x * bS;                                                 \
    const float ks  = keS - bSb * T.sc.y;                                          \
    const float wv  = T.vc - T.sc.x * ks;                                          \
    const float o   = (qeS - bSb * T.sc.z) + wv * T.sc.w;                          \
    const f2 bb2 = {bSb, bSb};                                                     \
    const f2 wv2 = {wv, wv};                                                       \
    s01 = e01 * (s01 - bb2 * k01) + wv2 * k01;                                     \
    s23 = e23 * (s23 - bb2 * k23) + wv2 * k23;                                     \
    if (rg == 0) {                                                                 \
        if (basis) {                                                               \
            u16 hi, lo; splitbf(o, hi, lo);                                        \
            rbh[oidx + (size_t)(SOFF) * 1024] = hi;                                \
            rbl[oidx + (size_t)(SOFF) * 1024] = lo;                                \
        } else {                                                                   \
            ov[oidx + (size_t)(SOFF) * 1024] = o;                                  \
        }                                                                          \
    }                                                                              \
  }

#define SBAR __builtin_amdgcn_sched_barrier(0)

__device__ __forceinline__ void stage_batch(
    const float* __restrict__ p0, char* ldsbuf, int t0, int w, int lane, int vg)
{
    for (int s = w; s < TOKB; s += 4) {
        const char* src = (const char*)(p0 + (size_t)(t0 + s) * RECSTRIDE);
        char* dst = ldsbuf + s * SLOTB;
        GLOAD_LDS16(src + lane * 16, dst);                               // k,e (1024B)
        if (lane < 32) GLOAD_LDS16(src + 1024 + lane * 16, dst + 1024);  // qe (512B)
        if (lane < 2)  GLOAD_LDS16(src + 1536 + vg * 32 + lane * 16, dst + 1536); // v slice
        if (lane == 0) GLOAD_LDS16(src + 2048, dst + 1568);              // sc
    }
}

// 768 blocks x 256 threads (3072 waves = 3/SIMD, 3 blocks/CU @ 50KB LDS).
__global__ __launch_bounds__(256) void scan_kernel(
    const float* __restrict__ sb, float* __restrict__ ov,
    u16* __restrict__ rbh, u16* __restrict__ rbl,
    u16* __restrict__ pTh, u16* __restrict__ pTl)
{
    __shared__ char lds[2 * TOKB * SLOTB];   // 51200 B

    const int tid = threadIdx.x;
    const int blk = blockIdx.x;
    const int cl = tid >> 5;      // 0..7
    const int rg = tid & 31;
    const int w = tid >> 6;
    const int lane = tid & 63;

    const int bh = blk & 15;
    const int gidx = blk >> 4;

    int vg, tstart, colx;
    bool chunk0, basis = false;
    if (gidx < 16) {
        colx = gidx * 8 + cl; vg = gidx; tstart = 0; chunk0 = true;
    } else {
        const int cg2 = gidx - 16;
        colx = cg2 * 8 + cl; vg = cg2 & 15; tstart = 1024; chunk0 = false;
        basis = colx >= 128;
    }
    const int b = bh >> 3, h = bh & 7;
    const size_t base = (size_t)b * 2048 * 8 + h;
    const float* p0 = sb + base * RECF + (size_t)tstart * RECSTRIDE;

    size_t oidx;
    if (chunk0)      oidx = base * 128 + colx;
    else if (!basis) oidx = base * 128 + (size_t)1048576 + colx;
    else             oidx = base * 128 + (colx - 128);

    const float vmask = basis ? 0.f : 1.f;
    f2 s01, s23;
    if (basis) {
        const int jb = colx - 128;
        s01.x = (rg * 4 + 0 == jb) ? 1.f : 0.f;
        s01.y = (rg * 4 + 1 == jb) ? 1.f : 0.f;
        s23.x = (rg * 4 + 2 == jb) ? 1.f : 0.f;
        s23.y = (rg * 4 + 3 == jb) ? 1.f : 0.f;
    } else { s01 = (f2){0.f, 0.f}; s23 = (f2){0.f, 0.f}; }

    stage_batch(p0, lds, 0, w, lane, vg);
    __syncthreads();

    int cur = 0;
    for (int t0 = 0; t0 < 1024; t0 += TOKB) {
        if (t0 + TOKB < 1024)
            stage_batch(p0, lds + (cur ^ 1) * (TOKB * SLOTB), t0 + TOKB, w, lane, vg);

        const char* bufp = lds + cur * (TOKB * SLOTB);
        TR A, B;
        ldtok(bufp, rg, cl, A); A.vc *= vmask; SBAR;
#pragma unroll
        for (int s = 0; s < TOKB; s += 2) {
            ldtok(bufp + (s + 1) * SLOTB, rg, cl, B); B.vc *= vmask; SBAR;
            STEP(A, s);
            if (s + 2 < TOKB) { ldtok(bufp + (s + 2) * SLOTB, rg, cl, A); A.vc *= vmask; SBAR; }
            STEP(B, s + 1);
        }
        __syncthreads();
        cur ^= 1;
        oidx += (size_t)TOKB * 1024;
    }

    if (chunk0) {
        u16 h0, l0, h1, l1, h2, l2, h3, l3;
        splitbf(s01.x, h0, l0); splitbf(s01.y, h1, l1);
        splitbf(s23.x, h2, l2); splitbf(s23.y, h3, l3);
        const size_t po = (size_t)bh * 16384 + (size_t)colx * 128 + rg * 4;
        su4 hv = {(short)h0, (short)h1, (short)h2, (short)h3};
        su4 lv = {(short)l0, (short)l1, (short)l2, (short)l3};
        *(su4*)(pTh + po) = hv;
        *(su4*)(pTl + po) = lv;
    }
}

// ---------------- post
__global__ __launch_bounds__(128) void post_kernel(
    const float* __restrict__ ov, const float* __restrict__ gate,
    const float* __restrict__ normw, u16* __restrict__ ybf)
{
    const int gid = blockIdx.x;
    const int h = gid & 7;
    const int row = gid >> 3;
    const int tid = threadIdx.x;
    const int col = h * 128 + tid;

    __shared__ float red[128];

    const float o = ov[(size_t)row * 1024 + col];
    const float y = o * sigmf(gate[(size_t)row * 1024 + col]);

    red[tid] = y * y;
    __syncthreads();
    for (int off = 64; off > 0; off >>= 1) {
        if (tid < off) red[tid] += red[tid + off];
        __syncthreads();
    }
    const float rms = rsqrtf(red[0] * (1.f / 128.f) + 1e-6f);
    ybf[(size_t)row * 1024 + col] = f2bf(y * rms * normw[col]);
}

extern "C" void kernel_launch(void* const* d_in, const int* in_sizes, int n_in,
                              void* d_out, int out_size, void* d_ws, size_t ws_size,
                              hipStream_t stream)
{
    const float* x     = (const float*)d_in[0];
    const float* Wq    = (const float*)d_in[1];
    const float* Wk    = (const float*)d_in[2];
    const float* Wv    = (const float*)d_in[3];
    const float* Wf1   = (const float*)d_in[4];
    const float* Wf2   = (const float*)d_in[5];
    const float* Wbeta = (const float*)d_in[6];
    const float* Wog1  = (const float*)d_in[7];
    const float* Wog2  = (const float*)d_in[8];
    const float* normw = (const float*)d_in[9];
    const float* Wo    = (const float*)d_in[10];
    float* out = (float*)d_out;

    float* ws    = (float*)d_ws;
    float* qkv   = ws;                                 // 12M f [4096x3072]
    float* sb    = qkv + 3 * SZT;                      // 17.04M f
    float* ovr   = sb + (size_t)32768 * RECF;          // 4M f
    float* rbspace = ovr + SZT;                        // 4M f -> rbh/rbl u16
    float* pbspace = rbspace + SZT;                    // 256K f -> pTh/pTl u16
    float* wot   = pbspace + 262144;                   // 0.5M f
    float* wcatT = wot + 524288;                       // 0.25M f
    float* wfog  = wcatT + 262144;                     // 0.25M f
    float* f1sp  = wfog + 262144;                      // 1M f
    float* betap = f1sp + 1048576;                     // 32K f
    float* xsp   = betap + 32768;                      // 4M f (xh/xl)

    float* f1og = sb;                                  // early (dead before prep)

    u16* WqkvTh = (u16*)ovr;
    u16* WqkvTl = WqkvTh + (size_t)3 * 1024 * 1024;
    float* fraw = ovr;

    u16* xh  = (u16*)xsp;
    u16* xl  = xh + SZT;

    u16* rbh = (u16*)rbspace;
    u16* rbl = rbh + SZT;
    u16* pTh = (u16*)pbspace;
    u16* pTl = pTh + 262144;

    u16* WoT    = (u16*)wot;
    u16* WcatTh = (u16*)wcatT;
    u16* WcatTl = WcatTh + (size_t)256 * 1024;
    u16* Wf2Th  = (u16*)wfog;
    u16* Wf2Tl  = Wf2Th + (size_t)1024 * 128;
    u16* Wog2Th = Wf2Tl + (size_t)1024 * 128;
    u16* Wog2Tl = Wog2Th + (size_t)1024 * 128;
    u16* f1ogh  = (u16*)f1sp;
    u16* f1ogl  = f1ogh + (size_t)4096 * 256;

    float* gate = qkv;
    u16*   ybf  = (u16*)(qkv + SZT);

    dim3 b256(256), b128(128);

    wtrans_split_qkv<<<dim3(32, 32, 3), b256, 0, stream>>>(Wq, Wk, Wv, WqkvTh, WqkvTl);
    wtrans<<<dim3(32, 32), b256, 0, stream>>>(Wo, WoT);
    conv_split<<<2048, b256, 0, stream>>>(x, xh, xl);
    wtrans_split4<<<dim3(128, 1, 4), b256, 0, stream>>>(
        Wf1, Wog1, Wf2, Wog2, WcatTh, WcatTl, Wf2Th, Wf2Tl, Wog2Th, Wog2Tl);
    beta_kernel<<<4096, b256, 0, stream>>>(x, Wbeta, betap);

    gemm_bf16_split<<<dim3(24, 32), b256, 0, stream>>>(xh, xl, WqkvTh, WqkvTl, qkv, 4096, 3072, 1024, 1024, 1024);
    gemm_bf16_split<<<dim3(2, 32), b256, 0, stream>>>(xh, xl, WcatTh, WcatTl, f1og, 4096, 256, 1024, 1024, 1024);
    conv_split<<<512, b256, 0, stream>>>(f1og, f1ogh, f1ogl);
    gemm_bf16_split<<<dim3(8, 32), b256, 0, stream>>>(f1ogh, f1ogl, Wf2Th, Wf2Tl, fraw, 4096, 1024, 128, 256, 128);

    prep_kernel<<<32768, b128, 0, stream>>>(qkv, fraw, betap, sb);
    gemm_bf16_split<<<dim3(8, 32), b256, 0, stream>>>(f1ogh + 128, f1ogl + 128, Wog2Th, Wog2Tl, gate, 4096, 1024, 128, 256, 128);

    scan_kernel<<<768, b256, 0, stream>>>(sb, ovr, rbh, rbl, pTh, pTl);

    corr_gemm<<<dim3(1, 8, 16), b256, 0, stream>>>(rbh, rbl, pTh, pTl, ovr);

    post_kernel<<<32768, b128, 0, stream>>>(ovr, gate, normw, ybf);

    gemm_bf16<<<dim3(8, 32), b256, 0, stream>>>(ybf, WoT, out, 4096, 1024, 1024);
}

// Round 17
// 643.279 us; speedup vs baseline: 1.2006x; 1.0415x over previous
//
#include <hip/hip_runtime.h>
#include <cmath>

// DenseRnn on MI355X. B=2, N=2048, D=1024, H=8, HD=128.
//
// Precision budget (R17): recurrence amplifies only k (direction in S-products)
// and e (decay). q,v,gate enter the output LINEARLY -> plain bf16 suffices
// (one 2^-9 rounding, no amplification). k and e keep 3-term bf16x2 split.
//
//  wtrans_plain3 (z=3): Wq,Wv -> WqvT plain; Wo -> WoT plain
//  wtrans_split_k: Wk -> bf16 hi/lo; wtrans_split4: Wf1,Wog1->WcatT; Wf2,Wog2->T
//  conv_split: x -> bf16 hi/lo
//  gemm_bf16 (plain): qv = xh@[Wq|Wv] (N=2048); gate = og1h@Wog2T
//  gemm_bf16_split: kraw = x@Wk; f1og = x@Wcat; fraw = f1@Wf2
//  beta_kernel; prep -> records sb[520] = {k,e,qe,v, sc@512}
//  scan (C=2): 32 lanes/col x 4 rows/lane, 768 x 256-thr blocks = 3 waves/SIMD,
//    builtin-DPP red32, packed-f32 STEP. Chunk1 basis cols emit r_t bf16;
//    chunk0 emits P0^T bf16.
//  corr_gemm: ov[chunk1] += r @ P0;  post: gated per-head RMS -> bf16
//  gemm_bf16: y@Wo -> out

#define SZT ((size_t)4096 * 1024)
#define RECF 520
#define RECSTRIDE 4160
#define TOKB 16
#define SLOTB 1600

typedef unsigned short u16;
typedef __attribute__((ext_vector_type(8))) short short8;
typedef __attribute__((ext_vector_type(4))) short su4;
typedef __attribute__((ext_vector_type(4))) float f32x4;
typedef __attribute__((ext_vector_type(2))) float f2;

__device__ __forceinline__ float sigmf(float x) { return 1.f / (1.f + expf(-x)); }
__device__ __forceinline__ float siluf(float x) { return x * sigmf(x); }
__device__ __forceinline__ u16 f2bf(float f) {
    unsigned int u = __float_as_uint(f);
    unsigned int r = (u + 0x7FFFu + ((u >> 16) & 1u)) >> 16;
    return (u16)r;
}
__device__ __forceinline__ float bf2f(u16 h) { return __uint_as_float((unsigned int)h << 16); }
__device__ __forceinline__ void splitbf(float f, u16& hi, u16& lo) {
    hi = f2bf(f);
    lo = f2bf(f - bf2f(hi));
}

#define GLOAD_LDS16(gp, lp) __builtin_amdgcn_global_load_lds( \
    (const __attribute__((address_space(1))) void*)(gp),      \
    (__attribute__((address_space(3))) void*)(lp), 16, 0, 0)

// ---------------- transpose bodies
__device__ __forceinline__ void wtrans_split_body(
    const float* __restrict__ W, u16* __restrict__ WTh, u16* __restrict__ WTl,
    int K, int N, int bx, int by)
{
    __shared__ float t[32][33];
    const int tx = threadIdx.x & 31, ty = threadIdx.x >> 5;
    const int n0 = bx * 32, k0 = by * 32;
#pragma unroll
    for (int i = 0; i < 4; i++)
        t[ty + i * 8][tx] = W[(size_t)(k0 + ty + i * 8) * N + n0 + tx];
    __syncthreads();
#pragma unroll
    for (int i = 0; i < 4; i++) {
        u16 hi, lo;
        splitbf(t[tx][ty + i * 8], hi, lo);
        WTh[(size_t)(n0 + ty + i * 8) * K + k0 + tx] = hi;
        WTl[(size_t)(n0 + ty + i * 8) * K + k0 + tx] = lo;
    }
}

// z=0: Wq -> WqvT rows 0-1023; z=1: Wv -> WqvT rows 1024-2047; z=2: Wo -> WoT
__global__ __launch_bounds__(256) void wtrans_plain3(
    const float* __restrict__ Wq, const float* __restrict__ Wv, const float* __restrict__ Wo,
    u16* __restrict__ WqvT, u16* __restrict__ WoT)
{
    const int z = blockIdx.z;
    const float* W = (z == 0) ? Wq : (z == 1) ? Wv : Wo;
    u16* WT = (z == 0) ? WqvT : (z == 1) ? WqvT + (size_t)1024 * 1024 : WoT;
    __shared__ float t[32][33];
    const int tx = threadIdx.x & 31, ty = threadIdx.x >> 5;
    const int n0 = blockIdx.x * 32, k0 = blockIdx.y * 32;
#pragma unroll
    for (int i = 0; i < 4; i++)
        t[ty + i * 8][tx] = W[(size_t)(k0 + ty + i * 8) * 1024 + n0 + tx];
    __syncthreads();
#pragma unroll
    for (int i = 0; i < 4; i++)
        WT[(size_t)(n0 + ty + i * 8) * 1024 + k0 + tx] = f2bf(t[tx][ty + i * 8]);
}

__global__ __launch_bounds__(256) void wtrans_split_k(
    const float* __restrict__ Wk, u16* __restrict__ WTh, u16* __restrict__ WTl)
{
    wtrans_split_body(Wk, WTh, WTl, 1024, 1024, blockIdx.x, blockIdx.y);
}

__global__ __launch_bounds__(256) void wtrans_split4(
    const float* __restrict__ Wf1, const float* __restrict__ Wog1,
    const float* __restrict__ Wf2, const float* __restrict__ Wog2,
    u16* __restrict__ WcatTh, u16* __restrict__ WcatTl,
    u16* __restrict__ Wf2Th, u16* __restrict__ Wf2Tl,
    u16* __restrict__ Wog2Th, u16* __restrict__ Wog2Tl)
{
    const int z = blockIdx.z;
    const float* W; u16 *Th, *Tl; int K, N;
    if (z == 0)      { W = Wf1;  Th = WcatTh; Tl = WcatTl; K = 1024; N = 128; }
    else if (z == 1) { W = Wog1; Th = WcatTh + (size_t)128 * 1024; Tl = WcatTl + (size_t)128 * 1024; K = 1024; N = 128; }
    else if (z == 2) { W = Wf2;  Th = Wf2Th;  Tl = Wf2Tl;  K = 128; N = 1024; }
    else             { W = Wog2; Th = Wog2Th; Tl = Wog2Tl; K = 128; N = 1024; }
    const int nbx = N / 32;
    wtrans_split_body(W, Th, Tl, K, N, blockIdx.x % nbx, blockIdx.x / nbx);
}

__global__ __launch_bounds__(256) void conv_split(
    const float* __restrict__ in, u16* __restrict__ oh, u16* __restrict__ ol)
{
    const size_t i = ((size_t)blockIdx.x * 256 + threadIdx.x) * 8;
    short8 rh, rl;
#pragma unroll
    for (int j = 0; j < 8; j++) {
        u16 hi, lo;
        splitbf(in[i + j], hi, lo);
        rh[j] = (short)hi; rl[j] = (short)lo;
    }
    *(short8*)&oh[i] = rh;
    *(short8*)&ol[i] = rl;
}

__global__ __launch_bounds__(256) void beta_kernel(
    const float* __restrict__ x, const float* __restrict__ Wbeta, float* __restrict__ beta)
{
    const int row = blockIdx.x;
    const int tid = threadIdx.x;
    const int lane = tid & 63, wid = tid >> 6;
    __shared__ float wsum[4][8];
    float4 xv = *(const float4*)&x[(size_t)row * 1024 + tid * 4];
    float p[8];
#pragma unroll
    for (int h = 0; h < 8; h++)
        p[h] = xv.x * Wbeta[(size_t)(tid * 4 + 0) * 8 + h]
             + xv.y * Wbeta[(size_t)(tid * 4 + 1) * 8 + h]
             + xv.z * Wbeta[(size_t)(tid * 4 + 2) * 8 + h]
             + xv.w * Wbeta[(size_t)(tid * 4 + 3) * 8 + h];
#pragma unroll
    for (int off = 32; off >= 1; off >>= 1)
#pragma unroll
        for (int h = 0; h < 8; h++) p[h] += __shfl_xor(p[h], off);
    if (lane == 0)
#pragma unroll
        for (int h = 0; h < 8; h++) wsum[wid][h] = p[h];
    __syncthreads();
    if (tid < 8) {
        float s = wsum[0][tid] + wsum[1][tid] + wsum[2][tid] + wsum[3][tid];
        beta[(size_t)row * 8 + tid] = 2.f * sigmf(s);
    }
}

// ---------------- split bf16 MFMA GEMM (3-term)
__global__ __launch_bounds__(256) void gemm_bf16_split(
    const u16* __restrict__ Ah, const u16* __restrict__ Al,
    const u16* __restrict__ BTh, const u16* __restrict__ BTl,
    float* __restrict__ C, int M, int N, int K, int lda, int ldb)
{
    __shared__ u16 AsH[128 * 32];
    __shared__ u16 AsL[128 * 32];
    __shared__ u16 BsH[128 * 32];
    __shared__ u16 BsL[128 * 32];
    const int tid = threadIdx.x;
    const int lane = tid & 63;
    const int w = tid >> 6;
    const int wr = w >> 1, wc = w & 1;
    const int row0 = blockIdx.y * 128;
    const int col0 = blockIdx.x * 128;
    const int mrow = lane & 15;
    const int kgrp = (lane >> 4) * 8;

    f32x4 acc[4][4] = {};

    const int off0 = w * 1024 + lane * 16;
    const int r0 = off0 >> 6, kl0 = (off0 & 63) >> 1;
    const int off1 = off0 + 4096;
    const int r1 = off1 >> 6, kl1 = (off1 & 63) >> 1;

    for (int kt = 0; kt < K; kt += 32) {
        GLOAD_LDS16(Ah  + (size_t)(row0 + r0) * lda + kt + kl0, (char*)AsH + w * 1024);
        GLOAD_LDS16(Ah  + (size_t)(row0 + r1) * lda + kt + kl1, (char*)AsH + w * 1024 + 4096);
        GLOAD_LDS16(Al  + (size_t)(row0 + r0) * lda + kt + kl0, (char*)AsL + w * 1024);
        GLOAD_LDS16(Al  + (size_t)(row0 + r1) * lda + kt + kl1, (char*)AsL + w * 1024 + 4096);
        GLOAD_LDS16(BTh + (size_t)(col0 + r0) * ldb + kt + kl0, (char*)BsH + w * 1024);
        GLOAD_LDS16(BTh + (size_t)(col0 + r1) * ldb + kt + kl1, (char*)BsH + w * 1024 + 4096);
        GLOAD_LDS16(BTl + (size_t)(col0 + r0) * ldb + kt + kl0, (char*)BsL + w * 1024);
        GLOAD_LDS16(BTl + (size_t)(col0 + r1) * ldb + kt + kl1, (char*)BsL + w * 1024 + 4096);
        __syncthreads();

        short8 aH[4], aL[4], bH[4], bL[4];
#pragma unroll
        for (int mi = 0; mi < 4; ++mi) {
            aH[mi] = *(const short8*)&AsH[(wr * 64 + mi * 16 + mrow) * 32 + kgrp];
            aL[mi] = *(const short8*)&AsL[(wr * 64 + mi * 16 + mrow) * 32 + kgrp];
        }
#pragma unroll
        for (int ni = 0; ni < 4; ++ni) {
            bH[ni] = *(const short8*)&BsH[(wc * 64 + ni * 16 + mrow) * 32 + kgrp];
            bL[ni] = *(const short8*)&BsL[(wc * 64 + ni * 16 + mrow) * 32 + kgrp];
        }
#pragma unroll
        for (int mi = 0; mi < 4; ++mi)
#pragma unroll
            for (int ni = 0; ni < 4; ++ni) {
                acc[mi][ni] = __builtin_amdgcn_mfma_f32_16x16x32_bf16(aH[mi], bH[ni], acc[mi][ni], 0, 0, 0);
                acc[mi][ni] = __builtin_amdgcn_mfma_f32_16x16x32_bf16(aL[mi], bH[ni], acc[mi][ni], 0, 0, 0);
                acc[mi][ni] = __builtin_amdgcn_mfma_f32_16x16x32_bf16(aH[mi], bL[ni], acc[mi][ni], 0, 0, 0);
            }
        __syncthreads();
    }

    const int crow = (lane >> 4) * 4;
#pragma unroll
    for (int mi = 0; mi < 4; ++mi)
#pragma unroll
        for (int ni = 0; ni < 4; ++ni)
#pragma unroll
            for (int j = 0; j < 4; ++j)
                C[(size_t)(row0 + wr * 64 + mi * 16 + crow + j) * N + col0 + wc * 64 + ni * 16 + mrow]
                    = acc[mi][ni][j];
}

// ---------------- correction GEMM
__global__ __launch_bounds__(256) void corr_gemm(
    const u16* __restrict__ Ah, const u16* __restrict__ Al,
    const u16* __restrict__ BTh, const u16* __restrict__ BTl,
    float* __restrict__ OV)
{
    __shared__ u16 AsH[128 * 32];
    __shared__ u16 AsL[128 * 32];
    __shared__ u16 BsH[128 * 32];
    __shared__ u16 BsL[128 * 32];
    const int tid = threadIdx.x;
    const int lane = tid & 63;
    const int w = tid >> 6;
    const int wr = w >> 1, wc = w & 1;
    const int row0 = blockIdx.y * 128;
    const int mrow = lane & 15;
    const int kgrp = (lane >> 4) * 8;

    const int bh = blockIdx.z;
    const int b = bh >> 3, h = bh & 7;
    const size_t aoff = (size_t)b * 2097152 + (size_t)h * 128;
    const size_t boff = (size_t)bh * 16384;
    const size_t coff = (size_t)b * 2097152 + (size_t)1048576 + (size_t)h * 128;

    f32x4 acc[4][4] = {};

    const int off0 = w * 1024 + lane * 16;
    const int r0 = off0 >> 6, kl0 = (off0 & 63) >> 1;
    const int off1 = off0 + 4096;
    const int r1 = off1 >> 6, kl1 = (off1 & 63) >> 1;

    for (int kt = 0; kt < 128; kt += 32) {
        GLOAD_LDS16(Ah  + aoff + (size_t)(row0 + r0) * 1024 + kt + kl0, (char*)AsH + w * 1024);
        GLOAD_LDS16(Ah  + aoff + (size_t)(row0 + r1) * 1024 + kt + kl1, (char*)AsH + w * 1024 + 4096);
        GLOAD_LDS16(Al  + aoff + (size_t)(row0 + r0) * 1024 + kt + kl0, (char*)AsL + w * 1024);
        GLOAD_LDS16(Al  + aoff + (size_t)(row0 + r1) * 1024 + kt + kl1, (char*)AsL + w * 1024 + 4096);
        GLOAD_LDS16(BTh + boff + (size_t)r0 * 128 + kt + kl0, (char*)BsH + w * 1024);
        GLOAD_LDS16(BTh + boff + (size_t)r1 * 128 + kt + kl1, (char*)BsH + w * 1024 + 4096);
        GLOAD_LDS16(BTl + boff + (size_t)r0 * 128 + kt + kl0, (char*)BsL + w * 1024);
        GLOAD_LDS16(BTl + boff + (size_t)r1 * 128 + kt + kl1, (char*)BsL + w * 1024 + 4096);
        __syncthreads();

        short8 aH[4], aL[4], bH[4], bL[4];
#pragma unroll
        for (int mi = 0; mi < 4; ++mi) {
            aH[mi] = *(const short8*)&AsH[(wr * 64 + mi * 16 + mrow) * 32 + kgrp];
            aL[mi] = *(const short8*)&AsL[(wr * 64 + mi * 16 + mrow) * 32 + kgrp];
        }
#pragma unroll
        for (int ni = 0; ni < 4; ++ni) {
            bH[ni] = *(const short8*)&BsH[(wc * 64 + ni * 16 + mrow) * 32 + kgrp];
            bL[ni] = *(const short8*)&BsL[(wc * 64 + ni * 16 + mrow) * 32 + kgrp];
        }
#pragma unroll
        for (int mi = 0; mi < 4; ++mi)
#pragma unroll
            for (int ni = 0; ni < 4; ++ni) {
                acc[mi][ni] = __builtin_amdgcn_mfma_f32_16x16x32_bf16(aH[mi], bH[ni], acc[mi][ni], 0, 0, 0);
                acc[mi][ni] = __builtin_amdgcn_mfma_f32_16x16x32_bf16(aL[mi], bH[ni], acc[mi][ni], 0, 0, 0);
                acc[mi][ni] = __builtin_amdgcn_mfma_f32_16x16x32_bf16(aH[mi], bL[ni], acc[mi][ni], 0, 0, 0);
            }
        __syncthreads();
    }

    const int crow = (lane >> 4) * 4;
#pragma unroll
    for (int mi = 0; mi < 4; ++mi)
#pragma unroll
        for (int ni = 0; ni < 4; ++ni)
#pragma unroll
            for (int j = 0; j < 4; ++j) {
                const size_t idx = coff + (size_t)(row0 + wr * 64 + mi * 16 + crow + j) * 1024
                                 + wc * 64 + ni * 16 + mrow;
                OV[idx] += acc[mi][ni][j];
            }
}

// ---------------- plain bf16 MFMA GEMM (lda/ldb parametrized)
__global__ __launch_bounds__(256) void gemm_bf16(
    const u16* __restrict__ A, const u16* __restrict__ BT, float* __restrict__ C,
    int M, int N, int K, int lda, int ldb)
{
    __shared__ u16 As[128 * 32];
    __shared__ u16 Bs[128 * 32];
    const int tid = threadIdx.x;
    const int lane = tid & 63;
    const int w = tid >> 6;
    const int wr = w >> 1, wc = w & 1;
    const int row0 = blockIdx.y * 128;
    const int col0 = blockIdx.x * 128;
    const int mrow = lane & 15;
    const int kgrp = (lane >> 4) * 8;

    f32x4 acc[4][4] = {};

    const int off0 = w * 1024 + lane * 16;
    const int r0 = off0 >> 6, kl0 = (off0 & 63) >> 1;
    const int off1 = off0 + 4096;
    const int r1 = off1 >> 6, kl1 = (off1 & 63) >> 1;

    for (int kt = 0; kt < K; kt += 32) {
        GLOAD_LDS16(A  + (size_t)(row0 + r0) * lda + kt + kl0, (char*)As + w * 1024);
        GLOAD_LDS16(A  + (size_t)(row0 + r1) * lda + kt + kl1, (char*)As + w * 1024 + 4096);
        GLOAD_LDS16(BT + (size_t)(col0 + r0) * ldb + kt + kl0, (char*)Bs + w * 1024);
        GLOAD_LDS16(BT + (size_t)(col0 + r1) * ldb + kt + kl1, (char*)Bs + w * 1024 + 4096);
        __syncthreads();

        short8 aF[4], bF[4];
#pragma unroll
        for (int mi = 0; mi < 4; ++mi)
            aF[mi] = *(const short8*)&As[(wr * 64 + mi * 16 + mrow) * 32 + kgrp];
#pragma unroll
        for (int ni = 0; ni < 4; ++ni)
            bF[ni] = *(const short8*)&Bs[(wc * 64 + ni * 16 + mrow) * 32 + kgrp];
#pragma unroll
        for (int mi = 0; mi < 4; ++mi)
#pragma unroll
            for (int ni = 0; ni < 4; ++ni)
                acc[mi][ni] = __builtin_amdgcn_mfma_f32_16x16x32_bf16(aF[mi], bF[ni], acc[mi][ni], 0, 0, 0);
        __syncthreads();
    }

    const int crow = (lane >> 4) * 4;
#pragma unroll
    for (int mi = 0; mi < 4; ++mi)
#pragma unroll
        for (int ni = 0; ni < 4; ++ni)
#pragma unroll
            for (int j = 0; j < 4; ++j)
                C[(size_t)(row0 + wr * 64 + mi * 16 + crow + j) * N + col0 + wc * 64 + ni * 16 + mrow]
                    = acc[mi][ni][j];
}

// ---------------- prep: q/v from qv [4096][2048], k from kraw [4096][1024]
__global__ __launch_bounds__(128) void prep_kernel(
    const float* __restrict__ qv, const float* __restrict__ kraw,
    const float* __restrict__ fraw, const float* __restrict__ beta,
    float* __restrict__ sb)
{
    const int gid = blockIdx.x;
    const int h = gid & 7;
    const int row = gid >> 3;
    const int tid = threadIdx.x;
    const int col = h * 128 + tid;

    __shared__ float red[3][128];

    const float ksil = siluf(kraw[(size_t)row * 1024 + col]);
    red[0][tid] = ksil * ksil;
    __syncthreads();
    for (int off = 64; off > 0; off >>= 1) {
        if (tid < off) red[0][tid] += red[0][tid + off];
        __syncthreads();
    }
    const float rn = rsqrtf(red[0][0] + 1e-6f);
    __syncthreads();

    const float kn = ksil * rn;
    const float e  = sigmf(fraw[(size_t)row * 1024 + col]);
    const float qs = siluf(qv[(size_t)row * 2048 + col]);
    const float vs = siluf(qv[(size_t)row * 2048 + 1024 + col]);
    const float kev = e * kn;
    const float qev = e * qs;

    red[0][tid] = kev * kn;   // c
    red[1][tid] = qs * kev;   // d1
    red[2][tid] = qs * kn;    // d2
    __syncthreads();
    for (int off = 64; off > 0; off >>= 1) {
        if (tid < off) {
            red[0][tid] += red[0][tid + off];
            red[1][tid] += red[1][tid + off];
            red[2][tid] += red[2][tid + off];
        }
        __syncthreads();
    }

    float* o = sb + (size_t)gid * RECF;
    o[tid]        = kn;
    o[128 + tid]  = e;
    o[256 + tid]  = qev;
    o[384 + tid]  = vs;
    if (tid == 0) {
        o[512] = beta[(size_t)row * 8 + h];
        o[513] = red[0][0];
        o[514] = red[1][0];
        o[515] = red[2][0];
    }
}

// ---------------- scan
__device__ __forceinline__ float red32(float x)
{
    x += __int_as_float(__builtin_amdgcn_mov_dpp(__float_as_int(x), 0xB1,  0xF, 0xF, true));
    x += __int_as_float(__builtin_amdgcn_mov_dpp(__float_as_int(x), 0x4E,  0xF, 0xF, true));
    x += __int_as_float(__builtin_amdgcn_mov_dpp(__float_as_int(x), 0x141, 0xF, 0xF, true));
    x += __int_as_float(__builtin_amdgcn_mov_dpp(__float_as_int(x), 0x140, 0xF, 0xF, true));
    x += __int_as_float(__builtin_amdgcn_ds_swizzle(__float_as_int(x), 0x401F));
    return x;
}

struct TR { float4 k, e, q, sc; float vc; };

__device__ __forceinline__ void ldtok(const char* __restrict__ rec, int rg, int cl, TR& T)
{
    T.k  = *(const float4*)(rec + rg * 16);
    T.e  = *(const float4*)(rec + 512 + rg * 16);
    T.q  = *(const float4*)(rec + 1024 + rg * 16);
    T.vc = *(const float*)(rec + 1536 + cl * 4);
    T.sc = *(const float4*)(rec + 1568);
}

#define STEP(T, SOFF)                                                              \
  {                                                                                \
    const f2 k01 = *(const f2*)&T.k.x; const f2 k23 = *(const f2*)&T.k.z;          \
    const f2 e01 = *(const f2*)&T.e.x; const f2 e23 = *(const f2*)&T.e.z;          \
    const f2 q01 = *(const f2*)&T.q.x; const f2 q23 = *(const f2*)&T.q.z;          \
    const f2 m01 = k01 * s01, m23 = k23 * s23;                                     \
    const f2 bS2 = m01 + m23;                                                      \
    const f2 em2 = e01 * m01 + e23 * m23;                                          \
    const f2 qs2 = q01 * s01 + q23 * s23;                                          \
    float bS  = bS2.x + bS2.y;                                                     \
    float keS = em2.x + em2.y;                                                     \
    float qeS = qs2.x + qs2.y;                                                     \
    bS = red32(bS); keS = red32(keS); qeS = red32(qeS);                            \
    const float bSb = T.sc.x * bS;                                                 \
    const float ks  = keS - bSb * T.sc.y;                                          \
    const float wv  = T.vc - T.sc.x * ks;                                          \
    const float o   = (qeS - bSb * T.sc.z) + wv * T.sc.w;                          \
    const f2 bb2 = {bSb, bSb};                                                     \
    const f2 wv2 = {wv, wv};                                                       \
    s01 = e01 * (s01 - bb2 * k01) + wv2 * k01;                                     \
    s23 = e23 * (s23 - bb2 * k23) + wv2 * k23;                                     \
    if (rg == 0) {                                                                 \
        if (basis) {                                                               \
            u16 hi, lo; splitbf(o, hi, lo);                                        \
            rbh[oidx + (size_t)(SOFF) * 1024] = hi;                                \
            rbl[oidx + (size_t)(SOFF) * 1024] = lo;                                \
        } else {                                                                   \
            ov[oidx + (size_t)(SOFF) * 1024] = o;                                  \
        }                                                                          \
    }                                                                              \
  }

#define SBAR __builtin_amdgcn_sched_barrier(0)

__device__ __forceinline__ void stage_batch(
    const float* __restrict__ p0, char* ldsbuf, int t0, int w, int lane, int vg)
{
    for (int s = w; s < TOKB; s += 4) {
        const char* src = (const char*)(p0 + (size_t)(t0 + s) * RECSTRIDE);
        char* dst = ldsbuf + s * SLOTB;
        GLOAD_LDS16(src + lane * 16, dst);
        if (lane < 32) GLOAD_LDS16(src + 1024 + lane * 16, dst + 1024);
        if (lane < 2)  GLOAD_LDS16(src + 1536 + vg * 32 + lane * 16, dst + 1536);
        if (lane == 0) GLOAD_LDS16(src + 2048, dst + 1568);
    }
}

__global__ __launch_bounds__(256) void scan_kernel(
    const float* __restrict__ sb, float* __restrict__ ov,
    u16* __restrict__ rbh, u16* __restrict__ rbl,
    u16* __restrict__ pTh, u16* __restrict__ pTl)
{
    __shared__ char lds[2 * TOKB * SLOTB];   // 51200 B

    const int tid = threadIdx.x;
    const int blk = blockIdx.x;
    const int cl = tid >> 5;
    const int rg = tid & 31;
    const int w = tid >> 6;
    const int lane = tid & 63;

    const int bh = blk & 15;
    const int gidx = blk >> 4;

    int vg, tstart, colx;
    bool chunk0, basis = false;
    if (gidx < 16) {
        colx = gidx * 8 + cl; vg = gidx; tstart = 0; chunk0 = true;
    } else {
        const int cg2 = gidx - 16;
        colx = cg2 * 8 + cl; vg = cg2 & 15; tstart = 1024; chunk0 = false;
        basis = colx >= 128;
    }
    const int b = bh >> 3, h = bh & 7;
    const size_t base = (size_t)b * 2048 * 8 + h;
    const float* p0 = sb + base * RECF + (size_t)tstart * RECSTRIDE;

    size_t oidx;
    if (chunk0)      oidx = base * 128 + colx;
    else if (!basis) oidx = base * 128 + (size_t)1048576 + colx;
    else             oidx = base * 128 + (colx - 128);

    const float vmask = basis ? 0.f : 1.f;
    f2 s01, s23;
    if (basis) {
        const int jb = colx - 128;
        s01.x = (rg * 4 + 0 == jb) ? 1.f : 0.f;
        s01.y = (rg * 4 + 1 == jb) ? 1.f : 0.f;
        s23.x = (rg * 4 + 2 == jb) ? 1.f : 0.f;
        s23.y = (rg * 4 + 3 == jb) ? 1.f : 0.f;
    } else { s01 = (f2){0.f, 0.f}; s23 = (f2){0.f, 0.f}; }

    stage_batch(p0, lds, 0, w, lane, vg);
    __syncthreads();

    int cur = 0;
    for (int t0 = 0; t0 < 1024; t0 += TOKB) {
        if (t0 + TOKB < 1024)
            stage_batch(p0, lds + (cur ^ 1) * (TOKB * SLOTB), t0 + TOKB, w, lane, vg);

        const char* bufp = lds + cur * (TOKB * SLOTB);
        TR A, B;
        ldtok(bufp, rg, cl, A); A.vc *= vmask; SBAR;
#pragma unroll
        for (int s = 0; s < TOKB; s += 2) {
            ldtok(bufp + (s + 1) * SLOTB, rg, cl, B); B.vc *= vmask; SBAR;
            STEP(A, s);
            if (s + 2 < TOKB) { ldtok(bufp + (s + 2) * SLOTB, rg, cl, A); A.vc *= vmask; SBAR; }
            STEP(B, s + 1);
        }
        __syncthreads();
        cur ^= 1;
        oidx += (size_t)TOKB * 1024;
    }

    if (chunk0) {
        u16 h0, l0, h1, l1, h2, l2, h3, l3;
        splitbf(s01.x, h0, l0); splitbf(s01.y, h1, l1);
        splitbf(s23.x, h2, l2); splitbf(s23.y, h3, l3);
        const size_t po = (size_t)bh * 16384 + (size_t)colx * 128 + rg * 4;
        su4 hv = {(short)h0, (short)h1, (short)h2, (short)h3};
        su4 lv = {(short)l0, (short)l1, (short)l2, (short)l3};
        *(su4*)(pTh + po) = hv;
        *(su4*)(pTl + po) = lv;
    }
}

// ---------------- post
__global__ __launch_bounds__(128) void post_kernel(
    const float* __restrict__ ov, const float* __restrict__ gate,
    const float* __restrict__ normw, u16* __restrict__ ybf)
{
    const int gid = blockIdx.x;
    const int h = gid & 7;
    const int row = gid >> 3;
    const int tid = threadIdx.x;
    const int col = h * 128 + tid;

    __shared__ float red[128];

    const float o = ov[(size_t)row * 1024 + col];
    const float y = o * sigmf(gate[(size_t)row * 1024 + col]);

    red[tid] = y * y;
    __syncthreads();
    for (int off = 64; off > 0; off >>= 1) {
        if (tid < off) red[tid] += red[tid + off];
        __syncthreads();
    }
    const float rms = rsqrtf(red[0] * (1.f / 128.f) + 1e-6f);
    ybf[(size_t)row * 1024 + col] = f2bf(y * rms * normw[col]);
}

extern "C" void kernel_launch(void* const* d_in, const int* in_sizes, int n_in,
                              void* d_out, int out_size, void* d_ws, size_t ws_size,
                              hipStream_t stream)
{
    const float* x     = (const float*)d_in[0];
    const float* Wq    = (const float*)d_in[1];
    const float* Wk    = (const float*)d_in[2];
    const float* Wv    = (const float*)d_in[3];
    const float* Wf1   = (const float*)d_in[4];
    const float* Wf2   = (const float*)d_in[5];
    const float* Wbeta = (const float*)d_in[6];
    const float* Wog1  = (const float*)d_in[7];
    const float* Wog2  = (const float*)d_in[8];
    const float* normw = (const float*)d_in[9];
    const float* Wo    = (const float*)d_in[10];
    float* out = (float*)d_out;

    float* ws    = (float*)d_ws;
    float* qvraw = ws;                                 // 8M f [4096x2048]
    float* kraw  = qvraw + 2 * SZT;                    // 4M f
    float* sb    = kraw + SZT;                         // 17.04M f (f1og early inside)
    float* ovr   = sb + (size_t)32768 * RECF;          // 4M f (weights early; fraw; then ov)
    float* rbspace = ovr + SZT;                        // 4M f -> rbh/rbl u16
    float* pbspace = rbspace + SZT;                    // 256K f -> pTh/pTl u16
    float* wot   = pbspace + 262144;                   // 0.5M f
    float* wcatT = wot + 524288;                       // 0.25M f
    float* wfog  = wcatT + 262144;                     // 0.25M f
    float* f1sp  = wfog + 262144;                      // 1M f
    float* betap = f1sp + 1048576;                     // 32K f
    float* xsp   = betap + 32768;                      // 4M f (xh/xl)

    float* f1og = sb;                                  // early (dead before prep)

    // weights early in ovr: WqvT plain (2M u16) + WkT hi/lo (2M u16) = 4M u16 = 2M f
    u16* WqvT = (u16*)ovr;
    u16* WkTh = WqvT + (size_t)2048 * 1024;
    u16* WkTl = WkTh + (size_t)1024 * 1024;
    float* fraw = ovr;                                 // after qv/k gemms

    u16* xh  = (u16*)xsp;
    u16* xl  = xh + SZT;

    u16* rbh = (u16*)rbspace;
    u16* rbl = rbh + SZT;
    u16* pTh = (u16*)pbspace;
    u16* pTl = pTh + 262144;

    u16* WoT    = (u16*)wot;
    u16* WcatTh = (u16*)wcatT;
    u16* WcatTl = WcatTh + (size_t)256 * 1024;
    u16* Wf2Th  = (u16*)wfog;
    u16* Wf2Tl  = Wf2Th + (size_t)1024 * 128;
    u16* Wog2Th = Wf2Tl + (size_t)1024 * 128;
    u16* Wog2Tl = Wog2Th + (size_t)1024 * 128;
    u16* f1ogh  = (u16*)f1sp;
    u16* f1ogl  = f1ogh + (size_t)4096 * 256;

    float* gate = qvraw;                               // qvraw dead after prep
    u16*   ybf  = (u16*)kraw;                          // kraw dead after prep

    dim3 b256(256), b128(128);

    wtrans_plain3<<<dim3(32, 32, 3), b256, 0, stream>>>(Wq, Wv, Wo, WqvT, WoT);
    wtrans_split_k<<<dim3(32, 32), b256, 0, stream>>>(Wk, WkTh, WkTl);
    conv_split<<<2048, b256, 0, stream>>>(x, xh, xl);
    wtrans_split4<<<dim3(128, 1, 4), b256, 0, stream>>>(
        Wf1, Wog1, Wf2, Wog2, WcatTh, WcatTl, Wf2Th, Wf2Tl, Wog2Th, Wog2Tl);
    beta_kernel<<<4096, b256, 0, stream>>>(x, Wbeta, betap);

    gemm_bf16<<<dim3(16, 32), b256, 0, stream>>>(xh, WqvT, qvraw, 4096, 2048, 1024, 1024, 1024);
    gemm_bf16_split<<<dim3(8, 32), b256, 0, stream>>>(xh, xl, WkTh, WkTl, kraw, 4096, 1024, 1024, 1024, 1024);
    gemm_bf16_split<<<dim3(2, 32), b256, 0, stream>>>(xh, xl, WcatTh, WcatTl, f1og, 4096, 256, 1024, 1024, 1024);
    conv_split<<<512, b256, 0, stream>>>(f1og, f1ogh, f1ogl);
    gemm_bf16_split<<<dim3(8, 32), b256, 0, stream>>>(f1ogh, f1ogl, Wf2Th, Wf2Tl, fraw, 4096, 1024, 128, 256, 128);

    prep_kernel<<<32768, b128, 0, stream>>>(qvraw, kraw, fraw, betap, sb);
    gemm_bf16<<<dim3(8, 32), b256, 0, stream>>>(f1ogh + 128, Wog2Th, gate, 4096, 1024, 128, 256, 128);

    scan_kernel<<<768, b256, 0, stream>>>(sb, ovr, rbh, rbl, pTh, pTl);

    corr_gemm<<<dim3(1, 8, 16), b256, 0, stream>>>(rbh, rbl, pTh, pTl, ovr);

    post_kernel<<<32768, b128, 0, stream>>>(ovr, gate, normw, ybf);

    gemm_bf16<<<dim3(8, 32), b256, 0, stream>>>(ybf, WoT, out, 4096, 1024, 1024, 1024, 1024);
}

// Round 18
// 637.673 us; speedup vs baseline: 1.2112x; 1.0088x over previous
//
#include <hip/hip_runtime.h>
#include <cmath>

// DenseRnn on MI355X. B=2, N=2048, D=1024, H=8, HD=128.
//
// Final structure (R18): fused prologue (all weight transposes + x-split + beta
// in ONE range-dispatched launch), merged prep/post blocks (2 units / 256 thr),
// precision-budgeted GEMMs (k,e split bf16x2; q,v,gate plain bf16), C=2 chunked
// scan (32 lanes/col, 3 waves/SIMD, DPP+swizzle reductions, packed-f32 STEP),
// per-stream MFMA correction, final y@Wo.

#define SZT ((size_t)4096 * 1024)
#define RECF 520
#define RECSTRIDE 4160
#define TOKB 16
#define SLOTB 1600

typedef unsigned short u16;
typedef __attribute__((ext_vector_type(8))) short short8;
typedef __attribute__((ext_vector_type(4))) short su4;
typedef __attribute__((ext_vector_type(4))) float f32x4;
typedef __attribute__((ext_vector_type(2))) float f2;

__device__ __forceinline__ float sigmf(float x) { return 1.f / (1.f + expf(-x)); }
__device__ __forceinline__ float siluf(float x) { return x * sigmf(x); }
__device__ __forceinline__ u16 f2bf(float f) {
    unsigned int u = __float_as_uint(f);
    unsigned int r = (u + 0x7FFFu + ((u >> 16) & 1u)) >> 16;
    return (u16)r;
}
__device__ __forceinline__ float bf2f(u16 h) { return __uint_as_float((unsigned int)h << 16); }
__device__ __forceinline__ void splitbf(float f, u16& hi, u16& lo) {
    hi = f2bf(f);
    lo = f2bf(f - bf2f(hi));
}

#define GLOAD_LDS16(gp, lp) __builtin_amdgcn_global_load_lds( \
    (const __attribute__((address_space(1))) void*)(gp),      \
    (__attribute__((address_space(3))) void*)(lp), 16, 0, 0)

// ---------------- fused prologue: one launch, range-dispatched.
// [0,3072)       : Wq/Wv/Wo plain transpose (1024 blocks each)
// [3072,4096)    : Wk split transpose
// [4096,6144)    : x -> bf16 hi/lo
// [6144,6656)    : Wf1/Wog1->WcatT, Wf2/Wog2 split transpose (128 blocks x 4)
// [6656,10752)   : beta = 2*sigmoid(x@Wbeta), one block per row
__global__ __launch_bounds__(256) void prologue_kernel(
    const float* __restrict__ x,
    const float* __restrict__ Wq, const float* __restrict__ Wk, const float* __restrict__ Wv,
    const float* __restrict__ Wf1, const float* __restrict__ Wf2,
    const float* __restrict__ Wbeta, const float* __restrict__ Wog1,
    const float* __restrict__ Wog2, const float* __restrict__ Wo,
    u16* __restrict__ WqvT, u16* __restrict__ WoT,
    u16* __restrict__ WkTh, u16* __restrict__ WkTl,
    u16* __restrict__ xh, u16* __restrict__ xl,
    u16* __restrict__ WcatTh, u16* __restrict__ WcatTl,
    u16* __restrict__ Wf2Th, u16* __restrict__ Wf2Tl,
    u16* __restrict__ Wog2Th, u16* __restrict__ Wog2Tl,
    float* __restrict__ beta)
{
    const int blk = blockIdx.x;
    __shared__ float t[32][33];

    if (blk < 3072) {
        // plain transpose: z=0 Wq -> WqvT[0:1024), z=1 Wv -> WqvT[1024:2048), z=2 Wo
        const int z = blk >> 10;
        const int r = blk & 1023;
        const int bx = r & 31, by = r >> 5;
        const float* W = (z == 0) ? Wq : (z == 1) ? Wv : Wo;
        u16* WT = (z == 0) ? WqvT : (z == 1) ? WqvT + (size_t)1024 * 1024 : WoT;
        const int tx = threadIdx.x & 31, ty = threadIdx.x >> 5;
        const int n0 = bx * 32, k0 = by * 32;
#pragma unroll
        for (int i = 0; i < 4; i++)
            t[ty + i * 8][tx] = W[(size_t)(k0 + ty + i * 8) * 1024 + n0 + tx];
        __syncthreads();
#pragma unroll
        for (int i = 0; i < 4; i++)
            WT[(size_t)(n0 + ty + i * 8) * 1024 + k0 + tx] = f2bf(t[tx][ty + i * 8]);
    } else if (blk < 4096) {
        // Wk split transpose
        const int r = blk - 3072;
        const int bx = r & 31, by = r >> 5;
        const int tx = threadIdx.x & 31, ty = threadIdx.x >> 5;
        const int n0 = bx * 32, k0 = by * 32;
#pragma unroll
        for (int i = 0; i < 4; i++)
            t[ty + i * 8][tx] = Wk[(size_t)(k0 + ty + i * 8) * 1024 + n0 + tx];
        __syncthreads();
#pragma unroll
        for (int i = 0; i < 4; i++) {
            u16 hi, lo;
            splitbf(t[tx][ty + i * 8], hi, lo);
            WkTh[(size_t)(n0 + ty + i * 8) * 1024 + k0 + tx] = hi;
            WkTl[(size_t)(n0 + ty + i * 8) * 1024 + k0 + tx] = lo;
        }
    } else if (blk < 6144) {
        // conv_split of x
        const size_t i = ((size_t)(blk - 4096) * 256 + threadIdx.x) * 8;
        short8 rh, rl;
#pragma unroll
        for (int j = 0; j < 8; j++) {
            u16 hi, lo;
            splitbf(x[i + j], hi, lo);
            rh[j] = (short)hi; rl[j] = (short)lo;
        }
        *(short8*)&xh[i] = rh;
        *(short8*)&xl[i] = rl;
    } else if (blk < 6656) {
        // split4: z=0 Wf1, z=1 Wog1 (K=1024,N=128); z=2 Wf2, z=3 Wog2 (K=128,N=1024)
        const int r = blk - 6144;
        const int z = r >> 7;
        const int inner = r & 127;
        const float* W; u16 *Th, *Tl; int K, N;
        if (z == 0)      { W = Wf1;  Th = WcatTh; Tl = WcatTl; K = 1024; N = 128; }
        else if (z == 1) { W = Wog1; Th = WcatTh + (size_t)128 * 1024; Tl = WcatTl + (size_t)128 * 1024; K = 1024; N = 128; }
        else if (z == 2) { W = Wf2;  Th = Wf2Th;  Tl = Wf2Tl;  K = 128; N = 1024; }
        else             { W = Wog2; Th = Wog2Th; Tl = Wog2Tl; K = 128; N = 1024; }
        const int nbx = N / 32;
        const int bx = inner % nbx, by = inner / nbx;
        const int tx = threadIdx.x & 31, ty = threadIdx.x >> 5;
        const int n0 = bx * 32, k0 = by * 32;
#pragma unroll
        for (int i = 0; i < 4; i++)
            t[ty + i * 8][tx] = W[(size_t)(k0 + ty + i * 8) * N + n0 + tx];
        __syncthreads();
#pragma unroll
        for (int i = 0; i < 4; i++) {
            u16 hi, lo;
            splitbf(t[tx][ty + i * 8], hi, lo);
            Th[(size_t)(n0 + ty + i * 8) * K + k0 + tx] = hi;
            Tl[(size_t)(n0 + ty + i * 8) * K + k0 + tx] = lo;
        }
    } else {
        // beta: one block per row
        const int row = blk - 6656;
        const int tid = threadIdx.x;
        const int lane = tid & 63, wid = tid >> 6;
        __shared__ float wsum[4][8];
        float4 xv = *(const float4*)&x[(size_t)row * 1024 + tid * 4];
        float p[8];
#pragma unroll
        for (int h = 0; h < 8; h++)
            p[h] = xv.x * Wbeta[(size_t)(tid * 4 + 0) * 8 + h]
                 + xv.y * Wbeta[(size_t)(tid * 4 + 1) * 8 + h]
                 + xv.z * Wbeta[(size_t)(tid * 4 + 2) * 8 + h]
                 + xv.w * Wbeta[(size_t)(tid * 4 + 3) * 8 + h];
#pragma unroll
        for (int off = 32; off >= 1; off >>= 1)
#pragma unroll
            for (int h = 0; h < 8; h++) p[h] += __shfl_xor(p[h], off);
        if (lane == 0)
#pragma unroll
            for (int h = 0; h < 8; h++) wsum[wid][h] = p[h];
        __syncthreads();
        if (tid < 8) {
            float s = wsum[0][tid] + wsum[1][tid] + wsum[2][tid] + wsum[3][tid];
            beta[(size_t)row * 8 + tid] = 2.f * sigmf(s);
        }
    }
}

// ---------------- fp32 -> bf16 hi/lo elementwise (f1og intermediate)
__global__ __launch_bounds__(256) void conv_split(
    const float* __restrict__ in, u16* __restrict__ oh, u16* __restrict__ ol)
{
    const size_t i = ((size_t)blockIdx.x * 256 + threadIdx.x) * 8;
    short8 rh, rl;
#pragma unroll
    for (int j = 0; j < 8; j++) {
        u16 hi, lo;
        splitbf(in[i + j], hi, lo);
        rh[j] = (short)hi; rl[j] = (short)lo;
    }
    *(short8*)&oh[i] = rh;
    *(short8*)&ol[i] = rl;
}

// ---------------- split bf16 MFMA GEMM (3-term)
__global__ __launch_bounds__(256) void gemm_bf16_split(
    const u16* __restrict__ Ah, const u16* __restrict__ Al,
    const u16* __restrict__ BTh, const u16* __restrict__ BTl,
    float* __restrict__ C, int M, int N, int K, int lda, int ldb)
{
    __shared__ u16 AsH[128 * 32];
    __shared__ u16 AsL[128 * 32];
    __shared__ u16 BsH[128 * 32];
    __shared__ u16 BsL[128 * 32];
    const int tid = threadIdx.x;
    const int lane = tid & 63;
    const int w = tid >> 6;
    const int wr = w >> 1, wc = w & 1;
    const int row0 = blockIdx.y * 128;
    const int col0 = blockIdx.x * 128;
    const int mrow = lane & 15;
    const int kgrp = (lane >> 4) * 8;

    f32x4 acc[4][4] = {};

    const int off0 = w * 1024 + lane * 16;
    const int r0 = off0 >> 6, kl0 = (off0 & 63) >> 1;
    const int off1 = off0 + 4096;
    const int r1 = off1 >> 6, kl1 = (off1 & 63) >> 1;

    for (int kt = 0; kt < K; kt += 32) {
        GLOAD_LDS16(Ah  + (size_t)(row0 + r0) * lda + kt + kl0, (char*)AsH + w * 1024);
        GLOAD_LDS16(Ah  + (size_t)(row0 + r1) * lda + kt + kl1, (char*)AsH + w * 1024 + 4096);
        GLOAD_LDS16(Al  + (size_t)(row0 + r0) * lda + kt + kl0, (char*)AsL + w * 1024);
        GLOAD_LDS16(Al  + (size_t)(row0 + r1) * lda + kt + kl1, (char*)AsL + w * 1024 + 4096);
        GLOAD_LDS16(BTh + (size_t)(col0 + r0) * ldb + kt + kl0, (char*)BsH + w * 1024);
        GLOAD_LDS16(BTh + (size_t)(col0 + r1) * ldb + kt + kl1, (char*)BsH + w * 1024 + 4096);
        GLOAD_LDS16(BTl + (size_t)(col0 + r0) * ldb + kt + kl0, (char*)BsL + w * 1024);
        GLOAD_LDS16(BTl + (size_t)(col0 + r1) * ldb + kt + kl1, (char*)BsL + w * 1024 + 4096);
        __syncthreads();

        short8 aH[4], aL[4], bH[4], bL[4];
#pragma unroll
        for (int mi = 0; mi < 4; ++mi) {
            aH[mi] = *(const short8*)&AsH[(wr * 64 + mi * 16 + mrow) * 32 + kgrp];
            aL[mi] = *(const short8*)&AsL[(wr * 64 + mi * 16 + mrow) * 32 + kgrp];
        }
#pragma unroll
        for (int ni = 0; ni < 4; ++ni) {
            bH[ni] = *(const short8*)&BsH[(wc * 64 + ni * 16 + mrow) * 32 + kgrp];
            bL[ni] = *(const short8*)&BsL[(wc * 64 + ni * 16 + mrow) * 32 + kgrp];
        }
#pragma unroll
        for (int mi = 0; mi < 4; ++mi)
#pragma unroll
            for (int ni = 0; ni < 4; ++ni) {
                acc[mi][ni] = __builtin_amdgcn_mfma_f32_16x16x32_bf16(aH[mi], bH[ni], acc[mi][ni], 0, 0, 0);
                acc[mi][ni] = __builtin_amdgcn_mfma_f32_16x16x32_bf16(aL[mi], bH[ni], acc[mi][ni], 0, 0, 0);
                acc[mi][ni] = __builtin_amdgcn_mfma_f32_16x16x32_bf16(aH[mi], bL[ni], acc[mi][ni], 0, 0, 0);
            }
        __syncthreads();
    }

    const int crow = (lane >> 4) * 4;
#pragma unroll
    for (int mi = 0; mi < 4; ++mi)
#pragma unroll
        for (int ni = 0; ni < 4; ++ni)
#pragma unroll
            for (int j = 0; j < 4; ++j)
                C[(size_t)(row0 + wr * 64 + mi * 16 + crow + j) * N + col0 + wc * 64 + ni * 16 + mrow]
                    = acc[mi][ni][j];
}

// ---------------- correction GEMM
__global__ __launch_bounds__(256) void corr_gemm(
    const u16* __restrict__ Ah, const u16* __restrict__ Al,
    const u16* __restrict__ BTh, const u16* __restrict__ BTl,
    float* __restrict__ OV)
{
    __shared__ u16 AsH[128 * 32];
    __shared__ u16 AsL[128 * 32];
    __shared__ u16 BsH[128 * 32];
    __shared__ u16 BsL[128 * 32];
    const int tid = threadIdx.x;
    const int lane = tid & 63;
    const int w = tid >> 6;
    const int wr = w >> 1, wc = w & 1;
    const int row0 = blockIdx.y * 128;
    const int mrow = lane & 15;
    const int kgrp = (lane >> 4) * 8;

    const int bh = blockIdx.z;
    const int b = bh >> 3, h = bh & 7;
    const size_t aoff = (size_t)b * 2097152 + (size_t)h * 128;
    const size_t boff = (size_t)bh * 16384;
    const size_t coff = (size_t)b * 2097152 + (size_t)1048576 + (size_t)h * 128;

    f32x4 acc[4][4] = {};

    const int off0 = w * 1024 + lane * 16;
    const int r0 = off0 >> 6, kl0 = (off0 & 63) >> 1;
    const int off1 = off0 + 4096;
    const int r1 = off1 >> 6, kl1 = (off1 & 63) >> 1;

    for (int kt = 0; kt < 128; kt += 32) {
        GLOAD_LDS16(Ah  + aoff + (size_t)(row0 + r0) * 1024 + kt + kl0, (char*)AsH + w * 1024);
        GLOAD_LDS16(Ah  + aoff + (size_t)(row0 + r1) * 1024 + kt + kl1, (char*)AsH + w * 1024 + 4096);
        GLOAD_LDS16(Al  + aoff + (size_t)(row0 + r0) * 1024 + kt + kl0, (char*)AsL + w * 1024);
        GLOAD_LDS16(Al  + aoff + (size_t)(row0 + r1) * 1024 + kt + kl1, (char*)AsL + w * 1024 + 4096);
        GLOAD_LDS16(BTh + boff + (size_t)r0 * 128 + kt + kl0, (char*)BsH + w * 1024);
        GLOAD_LDS16(BTh + boff + (size_t)r1 * 128 + kt + kl1, (char*)BsH + w * 1024 + 4096);
        GLOAD_LDS16(BTl + boff + (size_t)r0 * 128 + kt + kl0, (char*)BsL + w * 1024);
        GLOAD_LDS16(BTl + boff + (size_t)r1 * 128 + kt + kl1, (char*)BsL + w * 1024 + 4096);
        __syncthreads();

        short8 aH[4], aL[4], bH[4], bL[4];
#pragma unroll
        for (int mi = 0; mi < 4; ++mi) {
            aH[mi] = *(const short8*)&AsH[(wr * 64 + mi * 16 + mrow) * 32 + kgrp];
            aL[mi] = *(const short8*)&AsL[(wr * 64 + mi * 16 + mrow) * 32 + kgrp];
        }
#pragma unroll
        for (int ni = 0; ni < 4; ++ni) {
            bH[ni] = *(const short8*)&BsH[(wc * 64 + ni * 16 + mrow) * 32 + kgrp];
            bL[ni] = *(const short8*)&BsL[(wc * 64 + ni * 16 + mrow) * 32 + kgrp];
        }
#pragma unroll
        for (int mi = 0; mi < 4; ++mi)
#pragma unroll
            for (int ni = 0; ni < 4; ++ni) {
                acc[mi][ni] = __builtin_amdgcn_mfma_f32_16x16x32_bf16(aH[mi], bH[ni], acc[mi][ni], 0, 0, 0);
                acc[mi][ni] = __builtin_amdgcn_mfma_f32_16x16x32_bf16(aL[mi], bH[ni], acc[mi][ni], 0, 0, 0);
                acc[mi][ni] = __builtin_amdgcn_mfma_f32_16x16x32_bf16(aH[mi], bL[ni], acc[mi][ni], 0, 0, 0);
            }
        __syncthreads();
    }

    const int crow = (lane >> 4) * 4;
#pragma unroll
    for (int mi = 0; mi < 4; ++mi)
#pragma unroll
        for (int ni = 0; ni < 4; ++ni)
#pragma unroll
            for (int j = 0; j < 4; ++j) {
                const size_t idx = coff + (size_t)(row0 + wr * 64 + mi * 16 + crow + j) * 1024
                                 + wc * 64 + ni * 16 + mrow;
                OV[idx] += acc[mi][ni][j];
            }
}

// ---------------- plain bf16 MFMA GEMM (lda/ldb parametrized)
__global__ __launch_bounds__(256) void gemm_bf16(
    const u16* __restrict__ A, const u16* __restrict__ BT, float* __restrict__ C,
    int M, int N, int K, int lda, int ldb)
{
    __shared__ u16 As[128 * 32];
    __shared__ u16 Bs[128 * 32];
    const int tid = threadIdx.x;
    const int lane = tid & 63;
    const int w = tid >> 6;
    const int wr = w >> 1, wc = w & 1;
    const int row0 = blockIdx.y * 128;
    const int col0 = blockIdx.x * 128;
    const int mrow = lane & 15;
    const int kgrp = (lane >> 4) * 8;

    f32x4 acc[4][4] = {};

    const int off0 = w * 1024 + lane * 16;
    const int r0 = off0 >> 6, kl0 = (off0 & 63) >> 1;
    const int off1 = off0 + 4096;
    const int r1 = off1 >> 6, kl1 = (off1 & 63) >> 1;

    for (int kt = 0; kt < K; kt += 32) {
        GLOAD_LDS16(A  + (size_t)(row0 + r0) * lda + kt + kl0, (char*)As + w * 1024);
        GLOAD_LDS16(A  + (size_t)(row0 + r1) * lda + kt + kl1, (char*)As + w * 1024 + 4096);
        GLOAD_LDS16(BT + (size_t)(col0 + r0) * ldb + kt + kl0, (char*)Bs + w * 1024);
        GLOAD_LDS16(BT + (size_t)(col0 + r1) * ldb + kt + kl1, (char*)Bs + w * 1024 + 4096);
        __syncthreads();

        short8 aF[4], bF[4];
#pragma unroll
        for (int mi = 0; mi < 4; ++mi)
            aF[mi] = *(const short8*)&As[(wr * 64 + mi * 16 + mrow) * 32 + kgrp];
#pragma unroll
        for (int ni = 0; ni < 4; ++ni)
            bF[ni] = *(const short8*)&Bs[(wc * 64 + ni * 16 + mrow) * 32 + kgrp];
#pragma unroll
        for (int mi = 0; mi < 4; ++mi)
#pragma unroll
            for (int ni = 0; ni < 4; ++ni)
                acc[mi][ni] = __builtin_amdgcn_mfma_f32_16x16x32_bf16(aF[mi], bF[ni], acc[mi][ni], 0, 0, 0);
        __syncthreads();
    }

    const int crow = (lane >> 4) * 4;
#pragma unroll
    for (int mi = 0; mi < 4; ++mi)
#pragma unroll
        for (int ni = 0; ni < 4; ++ni)
#pragma unroll
            for (int j = 0; j < 4; ++j)
                C[(size_t)(row0 + wr * 64 + mi * 16 + crow + j) * N + col0 + wc * 64 + ni * 16 + mrow]
                    = acc[mi][ni][j];
}

// ---------------- prep: 2 (row,h) units per 256-thr block
__global__ __launch_bounds__(256) void prep_kernel(
    const float* __restrict__ qv, const float* __restrict__ kraw,
    const float* __restrict__ fraw, const float* __restrict__ beta,
    float* __restrict__ sb)
{
    const int unit = threadIdx.x >> 7;
    const int tid = threadIdx.x & 127;
    const int gid = blockIdx.x * 2 + unit;
    const int h = gid & 7;
    const int row = gid >> 3;
    const int col = h * 128 + tid;

    __shared__ float red[2][3][128];

    const float ksil = siluf(kraw[(size_t)row * 1024 + col]);
    red[unit][0][tid] = ksil * ksil;
    __syncthreads();
    for (int off = 64; off > 0; off >>= 1) {
        if (tid < off) red[unit][0][tid] += red[unit][0][tid + off];
        __syncthreads();
    }
    const float rn = rsqrtf(red[unit][0][0] + 1e-6f);
    __syncthreads();

    const float kn = ksil * rn;
    const float e  = sigmf(fraw[(size_t)row * 1024 + col]);
    const float qs = siluf(qv[(size_t)row * 2048 + col]);
    const float vs = siluf(qv[(size_t)row * 2048 + 1024 + col]);
    const float kev = e * kn;
    const float qev = e * qs;

    red[unit][0][tid] = kev * kn;   // c
    red[unit][1][tid] = qs * kev;   // d1
    red[unit][2][tid] = qs * kn;    // d2
    __syncthreads();
    for (int off = 64; off > 0; off >>= 1) {
        if (tid < off) {
            red[unit][0][tid] += red[unit][0][tid + off];
            red[unit][1][tid] += red[unit][1][tid + off];
            red[unit][2][tid] += red[unit][2][tid + off];
        }
        __syncthreads();
    }

    float* o = sb + (size_t)gid * RECF;
    o[tid]        = kn;
    o[128 + tid]  = e;
    o[256 + tid]  = qev;
    o[384 + tid]  = vs;
    if (tid == 0) {
        o[512] = beta[(size_t)row * 8 + h];
        o[513] = red[unit][0][0];
        o[514] = red[unit][1][0];
        o[515] = red[unit][2][0];
    }
}

// ---------------- scan
__device__ __forceinline__ float red32(float x)
{
    x += __int_as_float(__builtin_amdgcn_mov_dpp(__float_as_int(x), 0xB1,  0xF, 0xF, true));
    x += __int_as_float(__builtin_amdgcn_mov_dpp(__float_as_int(x), 0x4E,  0xF, 0xF, true));
    x += __int_as_float(__builtin_amdgcn_mov_dpp(__float_as_int(x), 0x141, 0xF, 0xF, true));
    x += __int_as_float(__builtin_amdgcn_mov_dpp(__float_as_int(x), 0x140, 0xF, 0xF, true));
    x += __int_as_float(__builtin_amdgcn_ds_swizzle(__float_as_int(x), 0x401F));
    return x;
}

struct TR { float4 k, e, q, sc; float vc; };

__device__ __forceinline__ void ldtok(const char* __restrict__ rec, int rg, int cl, TR& T)
{
    T.k  = *(const float4*)(rec + rg * 16);
    T.e  = *(const float4*)(rec + 512 + rg * 16);
    T.q  = *(const float4*)(rec + 1024 + rg * 16);
    T.vc = *(const float*)(rec + 1536 + cl * 4);
    T.sc = *(const float4*)(rec + 1568);
}

#define STEP(T, SOFF)                                                              \
  {                                                                                \
    const f2 k01 = *(const f2*)&T.k.x; const f2 k23 = *(const f2*)&T.k.z;          \
    const f2 e01 = *(const f2*)&T.e.x; const f2 e23 = *(const f2*)&T.e.z;          \
    const f2 q01 = *(const f2*)&T.q.x; const f2 q23 = *(const f2*)&T.q.z;          \
    const f2 m01 = k01 * s01, m23 = k23 * s23;                                     \
    const f2 bS2 = m01 + m23;                                                      \
    const f2 em2 = e01 * m01 + e23 * m23;                                          \
    const f2 qs2 = q01 * s01 + q23 * s23;                                          \
    float bS  = bS2.x + bS2.y;                                                     \
    float keS = em2.x + em2.y;                                                     \
    float qeS = qs2.x + qs2.y;                                                     \
    bS = red32(bS); keS = red32(keS); qeS = red32(qeS);                            \
    const float bSb = T.sc.x * bS;                                                 \
    const float ks  = keS - bSb * T.sc.y;                                          \
    const float wv  = T.vc - T.sc.x * ks;                                          \
    const float o   = (qeS - bSb * T.sc.z) + wv * T.sc.w;                          \
    const f2 bb2 = {bSb, bSb};                                                     \
    const f2 wv2 = {wv, wv};                                                       \
    s01 = e01 * (s01 - bb2 * k01) + wv2 * k01;                                     \
    s23 = e23 * (s23 - bb2 * k23) + wv2 * k23;                                     \
    if (rg == 0) {                                                                 \
        if (basis) {                                                               \
            u16 hi, lo; splitbf(o, hi, lo);                                        \
            rbh[oidx + (size_t)(SOFF) * 1024] = hi;                                \
            rbl[oidx + (size_t)(SOFF) * 1024] = lo;                                \
        } else {                                                                   \
            ov[oidx + (size_t)(SOFF) * 1024] = o;                                  \
        }                                                                          \
    }                                                                              \
  }

#define SBAR __builtin_amdgcn_sched_barrier(0)

__device__ __forceinline__ void stage_batch(
    const float* __restrict__ p0, char* ldsbuf, int t0, int w, int lane, int vg)
{
    for (int s = w; s < TOKB; s += 4) {
        const char* src = (const char*)(p0 + (size_t)(t0 + s) * RECSTRIDE);
        char* dst = ldsbuf + s * SLOTB;
        GLOAD_LDS16(src + lane * 16, dst);
        if (lane < 32) GLOAD_LDS16(src + 1024 + lane * 16, dst + 1024);
        if (lane < 2)  GLOAD_LDS16(src + 1536 + vg * 32 + lane * 16, dst + 1536);
        if (lane == 0) GLOAD_LDS16(src + 2048, dst + 1568);
    }
}

__global__ __launch_bounds__(256) void scan_kernel(
    const float* __restrict__ sb, float* __restrict__ ov,
    u16* __restrict__ rbh, u16* __restrict__ rbl,
    u16* __restrict__ pTh, u16* __restrict__ pTl)
{
    __shared__ char lds[2 * TOKB * SLOTB];   // 51200 B

    const int tid = threadIdx.x;
    const int blk = blockIdx.x;
    const int cl = tid >> 5;
    const int rg = tid & 31;
    const int w = tid >> 6;
    const int lane = tid & 63;

    const int bh = blk & 15;
    const int gidx = blk >> 4;

    int vg, tstart, colx;
    bool chunk0, basis = false;
    if (gidx < 16) {
        colx = gidx * 8 + cl; vg = gidx; tstart = 0; chunk0 = true;
    } else {
        const int cg2 = gidx - 16;
        colx = cg2 * 8 + cl; vg = cg2 & 15; tstart = 1024; chunk0 = false;
        basis = colx >= 128;
    }
    const int b = bh >> 3, h = bh & 7;
    const size_t base = (size_t)b * 2048 * 8 + h;
    const float* p0 = sb + base * RECF + (size_t)tstart * RECSTRIDE;

    size_t oidx;
    if (chunk0)      oidx = base * 128 + colx;
    else if (!basis) oidx = base * 128 + (size_t)1048576 + colx;
    else             oidx = base * 128 + (colx - 128);

    const float vmask = basis ? 0.f : 1.f;
    f2 s01, s23;
    if (basis) {
        const int jb = colx - 128;
        s01.x = (rg * 4 + 0 == jb) ? 1.f : 0.f;
        s01.y = (rg * 4 + 1 == jb) ? 1.f : 0.f;
        s23.x = (rg * 4 + 2 == jb) ? 1.f : 0.f;
        s23.y = (rg * 4 + 3 == jb) ? 1.f : 0.f;
    } else { s01 = (f2){0.f, 0.f}; s23 = (f2){0.f, 0.f}; }

    stage_batch(p0, lds, 0, w, lane, vg);
    __syncthreads();

    int cur = 0;
    for (int t0 = 0; t0 < 1024; t0 += TOKB) {
        if (t0 + TOKB < 1024)
            stage_batch(p0, lds + (cur ^ 1) * (TOKB * SLOTB), t0 + TOKB, w, lane, vg);

        const char* bufp = lds + cur * (TOKB * SLOTB);
        TR A, B;
        ldtok(bufp, rg, cl, A); A.vc *= vmask; SBAR;
#pragma unroll
        for (int s = 0; s < TOKB; s += 2) {
            ldtok(bufp + (s + 1) * SLOTB, rg, cl, B); B.vc *= vmask; SBAR;
            STEP(A, s);
            if (s + 2 < TOKB) { ldtok(bufp + (s + 2) * SLOTB, rg, cl, A); A.vc *= vmask; SBAR; }
            STEP(B, s + 1);
        }
        __syncthreads();
        cur ^= 1;
        oidx += (size_t)TOKB * 1024;
    }

    if (chunk0) {
        u16 h0, l0, h1, l1, h2, l2, h3, l3;
        splitbf(s01.x, h0, l0); splitbf(s01.y, h1, l1);
        splitbf(s23.x, h2, l2); splitbf(s23.y, h3, l3);
        const size_t po = (size_t)bh * 16384 + (size_t)colx * 128 + rg * 4;
        su4 hv = {(short)h0, (short)h1, (short)h2, (short)h3};
        su4 lv = {(short)l0, (short)l1, (short)l2, (short)l3};
        *(su4*)(pTh + po) = hv;
        *(su4*)(pTl + po) = lv;
    }
}

// ---------------- post: 2 (row,h) units per 256-thr block
__global__ __launch_bounds__(256) void post_kernel(
    const float* __restrict__ ov, const float* __restrict__ gate,
    const float* __restrict__ normw, u16* __restrict__ ybf)
{
    const int unit = threadIdx.x >> 7;
    const int tid = threadIdx.x & 127;
    const int gid = blockIdx.x * 2 + unit;
    const int h = gid & 7;
    const int row = gid >> 3;
    const int col = h * 128 + tid;

    __shared__ float red[2][128];

    const float o = ov[(size_t)row * 1024 + col];
    const float y = o * sigmf(gate[(size_t)row * 1024 + col]);

    red[unit][tid] = y * y;
    __syncthreads();
    for (int off = 64; off > 0; off >>= 1) {
        if (tid < off) red[unit][tid] += red[unit][tid + off];
        __syncthreads();
    }
    const float rms = rsqrtf(red[unit][0] * (1.f / 128.f) + 1e-6f);
    ybf[(size_t)row * 1024 + col] = f2bf(y * rms * normw[col]);
}

extern "C" void kernel_launch(void* const* d_in, const int* in_sizes, int n_in,
                              void* d_out, int out_size, void* d_ws, size_t ws_size,
                              hipStream_t stream)
{
    const float* x     = (const float*)d_in[0];
    const float* Wq    = (const float*)d_in[1];
    const float* Wk    = (const float*)d_in[2];
    const float* Wv    = (const float*)d_in[3];
    const float* Wf1   = (const float*)d_in[4];
    const float* Wf2   = (const float*)d_in[5];
    const float* Wbeta = (const float*)d_in[6];
    const float* Wog1  = (const float*)d_in[7];
    const float* Wog2  = (const float*)d_in[8];
    const float* normw = (const float*)d_in[9];
    const float* Wo    = (const float*)d_in[10];
    float* out = (float*)d_out;

    float* ws    = (float*)d_ws;
    float* qvraw = ws;                                 // 8M f [4096x2048]
    float* kraw  = qvraw + 2 * SZT;                    // 4M f
    float* sb    = kraw + SZT;                         // 17.04M f (f1og early inside)
    float* ovr   = sb + (size_t)32768 * RECF;          // 4M f (weights early; fraw; then ov)
    float* rbspace = ovr + SZT;                        // 4M f -> rbh/rbl u16
    float* pbspace = rbspace + SZT;                    // 256K f -> pTh/pTl u16
    float* wot   = pbspace + 262144;                   // 0.5M f
    float* wcatT = wot + 524288;                       // 0.25M f
    float* wfog  = wcatT + 262144;                     // 0.25M f
    float* f1sp  = wfog + 262144;                      // 1M f
    float* betap = f1sp + 1048576;                     // 32K f
    float* xsp   = betap + 32768;                      // 4M f (xh/xl)

    float* f1og = sb;                                  // early (dead before prep)

    u16* WqvT = (u16*)ovr;
    u16* WkTh = WqvT + (size_t)2048 * 1024;
    u16* WkTl = WkTh + (size_t)1024 * 1024;
    float* fraw = ovr;                                 // after qv/k gemms

    u16* xh  = (u16*)xsp;
    u16* xl  = xh + SZT;

    u16* rbh = (u16*)rbspace;
    u16* rbl = rbh + SZT;
    u16* pTh = (u16*)pbspace;
    u16* pTl = pTh + 262144;

    u16* WoT    = (u16*)wot;
    u16* WcatTh = (u16*)wcatT;
    u16* WcatTl = WcatTh + (size_t)256 * 1024;
    u16* Wf2Th  = (u16*)wfog;
    u16* Wf2Tl  = Wf2Th + (size_t)1024 * 128;
    u16* Wog2Th = Wf2Tl + (size_t)1024 * 128;
    u16* Wog2Tl = Wog2Th + (size_t)1024 * 128;
    u16* f1ogh  = (u16*)f1sp;
    u16* f1ogl  = f1ogh + (size_t)4096 * 256;

    float* gate = qvraw;                               // qvraw dead after prep
    u16*   ybf  = (u16*)kraw;                          // kraw dead after prep

    dim3 b256(256);

    prologue_kernel<<<10752, b256, 0, stream>>>(
        x, Wq, Wk, Wv, Wf1, Wf2, Wbeta, Wog1, Wog2, Wo,
        WqvT, WoT, WkTh, WkTl, xh, xl,
        WcatTh, WcatTl, Wf2Th, Wf2Tl, Wog2Th, Wog2Tl, betap);

    gemm_bf16<<<dim3(16, 32), b256, 0, stream>>>(xh, WqvT, qvraw, 4096, 2048, 1024, 1024, 1024);
    gemm_bf16_split<<<dim3(8, 32), b256, 0, stream>>>(xh, xl, WkTh, WkTl, kraw, 4096, 1024, 1024, 1024, 1024);
    gemm_bf16_split<<<dim3(2, 32), b256, 0, stream>>>(xh, xl, WcatTh, WcatTl, f1og, 4096, 256, 1024, 1024, 1024);
    conv_split<<<512, b256, 0, stream>>>(f1og, f1ogh, f1ogl);
    gemm_bf16_split<<<dim3(8, 32), b256, 0, stream>>>(f1ogh, f1ogl, Wf2Th, Wf2Tl, fraw, 4096, 1024, 128, 256, 128);

    prep_kernel<<<16384, b256, 0, stream>>>(qvraw, kraw, fraw, betap, sb);
    gemm_bf16<<<dim3(8, 32), b256, 0, stream>>>(f1ogh + 128, Wog2Th, gate, 4096, 1024, 128, 256, 128);

    scan_kernel<<<768, b256, 0, stream>>>(sb, ovr, rbh, rbl, pTh, pTl);

    corr_gemm<<<dim3(1, 8, 16), b256, 0, stream>>>(rbh, rbl, pTh, pTl, ovr);

    post_kernel<<<16384, b256, 0, stream>>>(ovr, gate, normw, ybf);

    gemm_bf16<<<dim3(8, 32), b256, 0, stream>>>(ybf, WoT, out, 4096, 1024, 1024, 1024, 1024);
}